// Round 1
// baseline (1897.134 us; speedup 1.0000x reference)
//
#include <hip/hip_runtime.h>
#include <math.h>

#define BB 2
#define CC 128
#define HH 60
#define WW 80
#define NN 3072
#define TT 16.0f
#define SS 81
#define HW (HH*WW)
#define RN 16
#define MT 64

__device__ __forceinline__ void bsetup(float cn, int L, int& i0, int& i1, float& w){
    float x = (cn + 1.0f) * 0.5f * (float)(L - 1);
    float x0 = floorf(x);
    w = x - x0;
    int xi = (int)x0;
    i0 = xi < 0 ? 0 : (xi > L - 1 ? L - 1 : xi);
    i1 = (i0 + 1 > L - 1) ? L - 1 : (i0 + 1);
}

// Per-pixel L2-norm over C, scale by T, write transposed (B,H,W,C).
__global__ __launch_bounds__(128) void k_normT(const float* __restrict__ xf1, const float* __restrict__ xf2,
                        float* __restrict__ xf1t, float* __restrict__ xf2t){
    int idx = blockIdx.x;
    int map = idx / (BB*HW);
    int pix = idx % (BB*HW);
    const float* src = map ? xf2 : xf1;
    float* dst = map ? xf2t : xf1t;
    int b = pix / HW, hw = pix % HW;
    int c = threadIdx.x;
    float v = src[(size_t)(b*CC + c)*HW + hw];
    __shared__ float red[128];
    red[c] = v*v;
    __syncthreads();
    #pragma unroll
    for(int s=64; s>0; s>>=1){ if(c<s) red[c]+=red[c+s]; __syncthreads(); }
    float nrm = TT / sqrtf(red[0] + 1e-12f);
    dst[(size_t)pix*CC + c] = v * nrm;
}

// Bilinear sample raw map at coords, L2-normalize over C -> f; also write denormed coords.
__global__ __launch_bounds__(128) void k_feats(
        const float* __restrict__ xf, const float* __restrict__ cn,
        float* __restrict__ fOut, float* __restrict__ coordOut,
        const int* __restrict__ hI, const int* __restrict__ wI){
    int bn = blockIdx.x;
    int b = bn / NN;
    int c = threadIdx.x;
    float cnx = cn[(size_t)bn*2+0], cny = cn[(size_t)bn*2+1];
    int x0,x1,y0,y1; float wx,wy;
    bsetup(cnx, WW, x0,x1,wx);
    bsetup(cny, HH, y0,y1,wy);
    const float* base = xf + ((size_t)b*CC + c)*HW;
    float f00 = base[y0*WW+x0], f01 = base[y0*WW+x1];
    float f10 = base[y1*WW+x0], f11 = base[y1*WW+x1];
    float f = f00*(1.f-wx)*(1.f-wy) + f01*wx*(1.f-wy) + f10*(1.f-wx)*wy + f11*wx*wy;
    __shared__ float red[128];
    red[c] = f*f; __syncthreads();
    #pragma unroll
    for(int st=64; st>0; st>>=1){ if(c<st) red[c]+=red[c+st]; __syncthreads(); }
    float nrm = sqrtf(red[0] + 1e-12f);
    fOut[(size_t)bn*CC + c] = f / nrm;
    if(c==0){
        float h=(float)hI[0], w=(float)wI[0];
        coordOut[(size_t)bn*2+0] = (cnx+1.0f)*0.5f*(w-1.0f);
        coordOut[(size_t)bn*2+1] = (cny+1.0f)*0.5f*(h-1.0f);
    }
}

// One softmax pass: for each "row" r (RN per block), logits over all 3072 keys:
// l = T*dot(fR[r], fK[m]); accumulate softmax-weighted denormed key coords and
// normalized-coord^2; emit g, gn, std. Used for p12 (rows=f1,keys=f2,coords=coord2)
// and p21 (rows=f2,keys=f1,coords=coord1).
__global__ __launch_bounds__(256) void k_pass(
        const float* __restrict__ fR, const float* __restrict__ fK,
        const float* __restrict__ ckn,
        float* __restrict__ outG, float* __restrict__ outGn, float* __restrict__ outStd,
        const int* __restrict__ hI, const int* __restrict__ wI){
    int blk = blockIdx.x;
    int b  = blk / (NN/RN);
    int n0 = (blk % (NN/RN)) * RN;
    int tid = threadIdx.x;
    int ty = tid >> 4;   // 0..15 : row within block
    int tx = tid & 15;   // 0..15 : m-group (4 consecutive m each)

    __shared__ __align__(16) float f1s[RN][CC];
    __shared__ __align__(16) float f2s[MT][CC];
    __shared__ float part[RN][16][6];

    // stage f1 rows, swizzled: row r rotated by 2r float4-quads
    {
        const float4* src4 = (const float4*)(fR + ((size_t)b*NN + n0)*CC);
        for(int i=tid; i<RN*(CC/4); i+=256){
            int r = i >> 5, q = i & 31;
            ((float4*)f1s[r])[(q + 2*r) & 31] = src4[i];
        }
    }
    float hh = (float)hI[0], wimg = (float)wI[0];
    float sxc = 0.5f*(wimg-1.0f), syc = 0.5f*(hh-1.0f);

    float mx = -INFINITY, sum = 0.f, ax=0.f, ay=0.f, axx=0.f, ayy=0.f;

    for(int mt=0; mt<NN; mt+=MT){
        __syncthreads();
        {   // stage f2 tile, row r rotated by r>>2 quads
            const float4* src4 = (const float4*)(fK + ((size_t)b*NN + mt)*CC);
            for(int i=tid; i<MT*(CC/4); i+=256){
                int r = i >> 5, q = i & 31;
                ((float4*)f2s[r])[(q + (r>>2)) & 31] = src4[i];
            }
        }
        __syncthreads();

        int ml = tx*4;
        const float4* fa  = (const float4*)f1s[ty];
        const float4* fb0 = (const float4*)f2s[ml+0];
        const float4* fb1 = (const float4*)f2s[ml+1];
        const float4* fb2 = (const float4*)f2s[ml+2];
        const float4* fb3 = (const float4*)f2s[ml+3];
        int ra = (2*ty) & 31, rb = tx & 31;
        float d0=0.f,d1=0.f,d2=0.f,d3=0.f;
        #pragma unroll
        for(int cq=0; cq<32; cq++){
            int ia = (cq + ra) & 31, ib = (cq + rb) & 31;
            float4 a  = fa[ia];
            float4 v0 = fb0[ib], v1 = fb1[ib], v2 = fb2[ib], v3 = fb3[ib];
            d0 += a.x*v0.x + a.y*v0.y + a.z*v0.z + a.w*v0.w;
            d1 += a.x*v1.x + a.y*v1.y + a.z*v1.z + a.w*v1.w;
            d2 += a.x*v2.x + a.y*v2.y + a.z*v2.z + a.w*v2.w;
            d3 += a.x*v3.x + a.y*v3.y + a.z*v3.z + a.w*v3.w;
        }
        float dd[4] = {d0,d1,d2,d3};
        #pragma unroll
        for(int mi=0; mi<4; ++mi){
            float logit = TT*dd[mi];
            int m = mt + ml + mi;
            float cnx = ckn[((size_t)b*NN+m)*2+0];
            float cny = ckn[((size_t)b*NN+m)*2+1];
            float cx = (cnx+1.0f)*sxc;
            float cy = (cny+1.0f)*syc;
            if(logit <= mx){
                float w = __expf(logit - mx);
                sum += w; ax += w*cx; ay += w*cy; axx += w*cnx*cnx; ayy += w*cny*cny;
            } else {
                float r = __expf(mx - logit);
                sum = sum*r + 1.0f;
                ax = ax*r + cx; ay = ay*r + cy;
                axx = axx*r + cnx*cnx; ayy = ayy*r + cny*cny;
                mx = logit;
            }
        }
    }
    part[ty][tx][0]=mx;  part[ty][tx][1]=sum; part[ty][tx][2]=ax;
    part[ty][tx][3]=ay;  part[ty][tx][4]=axx; part[ty][tx][5]=ayy;
    __syncthreads();
    if(tx==0){
        float M=-INFINITY,S=0.f,AX=0.f,AY=0.f,AXX=0.f,AYY=0.f;
        for(int i=0;i<16;i++){
            float m2 = part[ty][i][0];
            float s2 = part[ty][i][1], x2=part[ty][i][2], y2=part[ty][i][3];
            float xx2=part[ty][i][4], yy2=part[ty][i][5];
            if(m2 <= M){
                float e = __expf(m2 - M);
                S += s2*e; AX += x2*e; AY += y2*e; AXX += xx2*e; AYY += yy2*e;
            } else {
                float r = (M==-INFINITY) ? 0.0f : __expf(M - m2);
                S = S*r + s2; AX = AX*r + x2; AY = AY*r + y2;
                AXX = AXX*r + xx2; AYY = AYY*r + yy2;
                M = m2;
            }
        }
        float gx = AX/S, gy = AY/S;
        float gnx = gx * (2.0f/(wimg-1.0f)) - 1.0f;
        float gny = gy * (2.0f/(hh-1.0f)) - 1.0f;
        float vx = AXX/S - gnx*gnx;
        float vy = AYY/S - gny*gny;
        float sd = sqrtf(fmaxf(vx,1e-6f)) + sqrtf(fmaxf(vy,1e-6f));
        size_t o = (size_t)b*NN + n0 + ty;
        outG[o*2+0]=gx;  outG[o*2+1]=gy;
        outGn[o*2+0]=gnx; outGn[o*2+1]=gny;
        outStd[o]=sd;
    }
}

// Window refinement: 81 bilinear samples of pre-normalized*T map around center,
// dot with query feature, softmax over samples, expectation+std of window coords.
__global__ __launch_bounds__(128) void k_win(
        const float* __restrict__ fQ, const float* __restrict__ fmapT,
        const float* __restrict__ center,
        float* __restrict__ outW, float* __restrict__ outStd,
        const int* __restrict__ hI, const int* __restrict__ wI){
    int bn = blockIdx.x;
    int b = bn / NN;
    int tid = threadIdx.x;
    __shared__ __align__(16) float fq[CC];
    fq[tid] = fQ[(size_t)bn*CC + tid];
    float gx = center[(size_t)bn*2+0], gy = center[(size_t)bn*2+1];
    __syncthreads();
    int s = (tid < SS) ? tid : (SS-1);
    float wcx = gx + (-0.125f + 0.03125f*(float)(s % 9));
    float wcy = gy + (-0.125f + 0.03125f*(float)(s / 9));
    int x0,x1,y0,y1; float wx,wy;
    bsetup(wcx, WW, x0,x1,wx);
    bsetup(wcy, HH, y0,y1,wy);
    const float4* p00 = (const float4*)(fmapT + ((size_t)(b*HW) + y0*WW + x0)*CC);
    const float4* p01 = (const float4*)(fmapT + ((size_t)(b*HW) + y0*WW + x1)*CC);
    const float4* p10 = (const float4*)(fmapT + ((size_t)(b*HW) + y1*WW + x0)*CC);
    const float4* p11 = (const float4*)(fmapT + ((size_t)(b*HW) + y1*WW + x1)*CC);
    float w00=(1.f-wx)*(1.f-wy), w01=wx*(1.f-wy), w10=(1.f-wx)*wy, w11=wx*wy;
    float d = 0.f;
    #pragma unroll
    for(int cq=0; cq<CC/4; cq++){
        float4 a = ((const float4*)fq)[cq];
        float4 v00 = p00[cq], v01 = p01[cq], v10 = p10[cq], v11 = p11[cq];
        d += a.x*(w00*v00.x + w01*v01.x + w10*v10.x + w11*v11.x);
        d += a.y*(w00*v00.y + w01*v01.y + w10*v10.y + w11*v11.y);
        d += a.z*(w00*v00.z + w01*v01.z + w10*v10.z + w11*v11.z);
        d += a.w*(w00*v00.w + w01*v01.w + w10*v10.w + w11*v11.w);
    }
    float logit = (tid < SS) ? d : -INFINITY;
    float M = logit;
    #pragma unroll
    for(int off=32; off>0; off>>=1) M = fmaxf(M, __shfl_down(M, off));
    __shared__ float mred[2];
    if((tid & 63) == 0) mred[tid>>6] = M;
    __syncthreads();
    M = fmaxf(mred[0], mred[1]);
    float w = (tid < SS) ? __expf(logit - M) : 0.f;
    float v0=w, v1=w*wcx, v2=w*wcy, v3=w*wcx*wcx, v4=w*wcy*wcy;
    #pragma unroll
    for(int off=32; off>0; off>>=1){
        v0 += __shfl_down(v0, off);
        v1 += __shfl_down(v1, off);
        v2 += __shfl_down(v2, off);
        v3 += __shfl_down(v3, off);
        v4 += __shfl_down(v4, off);
    }
    __shared__ float sred[2][5];
    if((tid&63)==0){ int wv=tid>>6; sred[wv][0]=v0; sred[wv][1]=v1; sred[wv][2]=v2; sred[wv][3]=v3; sred[wv][4]=v4; }
    __syncthreads();
    if(tid==0){
        float S = sred[0][0]+sred[1][0];
        float ex = (sred[0][1]+sred[1][1])/S;
        float ey = (sred[0][2]+sred[1][2])/S;
        float vx = (sred[0][3]+sred[1][3])/S - ex*ex;
        float vy = (sred[0][4]+sred[1][4])/S - ey*ey;
        float sd = sqrtf(fmaxf(vx,1e-6f)) + sqrtf(fmaxf(vy,1e-6f));
        float h = (float)hI[0], wimg = (float)wI[0];
        outW[(size_t)bn*2+0] = (ex+1.0f)*0.5f*(wimg-1.0f);
        outW[(size_t)bn*2+1] = (ey+1.0f)*0.5f*(h-1.0f);
        outStd[bn] = sd;
    }
}

__global__ void k_ones(float* __restrict__ p, int n){
    int i = blockIdx.x*256 + threadIdx.x;
    if(i < n) p[i] = 1.0f;
}

extern "C" void kernel_launch(void* const* d_in, const int* in_sizes, int n_in,
                              void* d_out, int out_size, void* d_ws, size_t ws_size,
                              hipStream_t stream){
    const float* xf1 = (const float*)d_in[0];
    const float* xf2 = (const float*)d_in[1];
    const float* c1n = (const float*)d_in[2];
    const float* c2n = (const float*)d_in[3];
    const int* h1 = (const int*)d_in[4];
    const int* w1 = (const int*)d_in[5];
    const int* h2 = (const int*)d_in[6];
    const int* w2 = (const int*)d_in[7];
    float* out = (float*)d_out;
    float* ws = (float*)d_ws;

    float* xf1t = ws;                              // B*HW*C
    float* xf2t = xf1t + (size_t)BB*HW*CC;
    float* f1   = xf2t + (size_t)BB*HW*CC;         // B*N*C
    float* f2   = f1 + (size_t)BB*NN*CC;

    float* o_coord1 = out + 0;
    float* o_coord2 = out + 12288;
    float* o_g1     = out + 24576;
    float* o_g2     = out + 36864;
    float* o_w1     = out + 49152;
    float* o_w2     = out + 61440;
    float* o_g1n    = out + 73728;
    float* o_g2n    = out + 86016;
    float* o_std1   = out + 98304;
    float* o_std2   = out + 104448;
    float* o_wstd1  = out + 110592;
    float* o_wstd2  = out + 116736;
    float* o_valid  = out + 122880;  // valid1 + valid2 contiguous (12288 ones)

    hipLaunchKernelGGL(k_normT, dim3(2*BB*HW), dim3(128), 0, stream, xf1, xf2, xf1t, xf2t);
    hipLaunchKernelGGL(k_feats, dim3(BB*NN), dim3(128), 0, stream, xf1, c1n, f1, o_coord1, h1, w1);
    hipLaunchKernelGGL(k_feats, dim3(BB*NN), dim3(128), 0, stream, xf2, c2n, f2, o_coord2, h2, w2);
    hipLaunchKernelGGL(k_pass, dim3(BB*NN/RN), dim3(256), 0, stream, f1, f2, c2n, o_g1, o_g1n, o_std1, h2, w2);
    hipLaunchKernelGGL(k_pass, dim3(BB*NN/RN), dim3(256), 0, stream, f2, f1, c1n, o_g2, o_g2n, o_std2, h1, w1);
    hipLaunchKernelGGL(k_win, dim3(BB*NN), dim3(128), 0, stream, f1, xf2t, o_g1n, o_w1, o_wstd1, h2, w2);
    hipLaunchKernelGGL(k_win, dim3(BB*NN), dim3(128), 0, stream, f2, xf1t, o_g2n, o_w2, o_wstd2, h1, w1);
    hipLaunchKernelGGL(k_ones, dim3((2*BB*NN+255)/256), dim3(256), 0, stream, o_valid, 2*BB*NN);
}

// Round 2
// 345.449 us; speedup vs baseline: 5.4918x; 5.4918x over previous
//
#include <hip/hip_runtime.h>
#include <hip/hip_bf16.h>
#include <math.h>

#define BB 2
#define CC 128
#define HH 60
#define WW 80
#define NN 3072
#define TT 16.0f
#define SS 81
#define HW (HH*WW)
#define NTILE 24   // 3072/128
#define LDA 136    // 128 + 8 bf16 pad -> 272B row stride, 16B aligned, 2-way bank (free)

typedef __attribute__((ext_vector_type(8))) short short8;
typedef __attribute__((ext_vector_type(4))) float f32x4;

__device__ __forceinline__ void bsetup(float cn, int L, int& i0, int& i1, float& w){
    float x = (cn + 1.0f) * 0.5f * (float)(L - 1);
    float x0 = floorf(x);
    w = x - x0;
    int xi = (int)x0;
    i0 = xi < 0 ? 0 : (xi > L - 1 ? L - 1 : xi);
    i1 = (i0 + 1 > L - 1) ? L - 1 : (i0 + 1);
}

// Per-pixel L2-norm over C, scale by T, write transposed (B,H,W,C).
__global__ __launch_bounds__(128) void k_normT(const float* __restrict__ xf1, const float* __restrict__ xf2,
                        float* __restrict__ xf1t, float* __restrict__ xf2t){
    int idx = blockIdx.x;
    int map = idx / (BB*HW);
    int pix = idx % (BB*HW);
    const float* src = map ? xf2 : xf1;
    float* dst = map ? xf2t : xf1t;
    int b = pix / HW, hw = pix % HW;
    int c = threadIdx.x;
    float v = src[(size_t)(b*CC + c)*HW + hw];
    __shared__ float red[128];
    red[c] = v*v;
    __syncthreads();
    #pragma unroll
    for(int s=64; s>0; s>>=1){ if(c<s) red[c]+=red[c+s]; __syncthreads(); }
    float nrm = TT / sqrtf(red[0] + 1e-12f);
    dst[(size_t)pix*CC + c] = v * nrm;
}

// Bilinear sample raw map at coords, L2-normalize over C -> bf16 features; also denormed coords.
__global__ __launch_bounds__(128) void k_feats(
        const float* __restrict__ xf, const float* __restrict__ cn,
        __hip_bfloat16* __restrict__ fOutB, float* __restrict__ coordOut,
        const int* __restrict__ hI, const int* __restrict__ wI){
    int bn = blockIdx.x;
    int b = bn / NN;
    int c = threadIdx.x;
    float cnx = cn[(size_t)bn*2+0], cny = cn[(size_t)bn*2+1];
    int x0,x1,y0,y1; float wx,wy;
    bsetup(cnx, WW, x0,x1,wx);
    bsetup(cny, HH, y0,y1,wy);
    const float* base = xf + ((size_t)b*CC + c)*HW;
    float f00 = base[y0*WW+x0], f01 = base[y0*WW+x1];
    float f10 = base[y1*WW+x0], f11 = base[y1*WW+x1];
    float f = f00*(1.f-wx)*(1.f-wy) + f01*wx*(1.f-wy) + f10*(1.f-wx)*wy + f11*wx*wy;
    __shared__ float red[128];
    red[c] = f*f; __syncthreads();
    #pragma unroll
    for(int st=64; st>0; st>>=1){ if(c<st) red[c]+=red[c+st]; __syncthreads(); }
    float nrm = sqrtf(red[0] + 1e-12f);
    fOutB[(size_t)bn*CC + c] = __float2bfloat16(f / nrm);
    if(c==0){
        float h=(float)hI[0], w=(float)wI[0];
        coordOut[(size_t)bn*2+0] = (cnx+1.0f)*0.5f*(w-1.0f);
        coordOut[(size_t)bn*2+1] = (cny+1.0f)*0.5f*(h-1.0f);
    }
}

// Fused correlation: ONE bf16-MFMA GEMM pass producing BOTH row (p12) and col (p21)
// partial softmax statistics. Logits bounded by ~T => fixed shift of 16, no online max.
// Partial stats: {sum, ax, ay, axx, ayy}; ax/ay weighted by DENORMED opposite coords,
// axx/ayy by NORMALIZED^2 opposite coords.
__global__ __launch_bounds__(256,2) void k_corr(
        const __hip_bfloat16* __restrict__ f1b, const __hip_bfloat16* __restrict__ f2b,
        const float* __restrict__ c1n, const float* __restrict__ c2n,
        float* __restrict__ wsRow, float* __restrict__ wsCol,
        const int* __restrict__ h1I, const int* __restrict__ w1I,
        const int* __restrict__ h2I, const int* __restrict__ w2I){
    int blk = blockIdx.x;
    int b   = blk / (NTILE*NTILE);
    int rem = blk % (NTILE*NTILE);
    int nt = rem / NTILE, mt = rem % NTILE;
    int n0 = nt*128, m0 = mt*128;
    int tid = threadIdx.x;
    int lane = tid & 63, wid = tid >> 6;
    int wr = wid >> 1, wc = wid & 1;
    int lr = lane & 15, lh = lane >> 4;

    __shared__ __align__(16) unsigned short As[128*LDA];
    __shared__ __align__(16) unsigned short Bs[128*LDA];
    __shared__ float cn1s[128*2];
    __shared__ float cn2s[128*2];
    __shared__ float rowPart[2][128][5];
    __shared__ float colPart[2][128][5];

    // ---- stage bf16 features into padded LDS (coalesced 16B loads) ----
    {
        const unsigned short* gA = (const unsigned short*)f1b + ((size_t)b*NN + n0)*CC;
        const unsigned short* gB = (const unsigned short*)f2b + ((size_t)b*NN + m0)*CC;
        #pragma unroll
        for(int it=0; it<8; ++it){
            int idx = tid + it*256;            // 128*16 chunks of 8 bf16
            int r = idx >> 4, q = idx & 15;
            *(uint4*)(As + r*LDA + q*8) = *(const uint4*)(gA + r*CC + q*8);
            *(uint4*)(Bs + r*LDA + q*8) = *(const uint4*)(gB + r*CC + q*8);
        }
        if(tid < 128){
            cn1s[tid*2+0] = c1n[((size_t)b*NN + n0 + tid)*2+0];
            cn1s[tid*2+1] = c1n[((size_t)b*NN + n0 + tid)*2+1];
        } else {
            int t = tid - 128;
            cn2s[t*2+0] = c2n[((size_t)b*NN + m0 + t)*2+0];
            cn2s[t*2+1] = c2n[((size_t)b*NN + m0 + t)*2+1];
        }
    }
    __syncthreads();

    // ---- MFMA: wave (wr,wc) computes 64x64 quadrant; acc[i][j][r] =
    //      dot(f1[n0+wr*64+i*16+lh*4+r], f2[m0+wc*64+j*16+lr]) ----
    f32x4 acc[4][4] = {};
    const unsigned short* aBase = As + (wr*64 + lr)*LDA + lh*8;
    const unsigned short* bBase = Bs + (wc*64 + lr)*LDA + lh*8;
    #pragma unroll
    for(int ks=0; ks<4; ++ks){
        short8 afr[4], bfr[4];
        #pragma unroll
        for(int i=0;i<4;i++) afr[i] = *(const short8*)(aBase + i*16*LDA + ks*32);
        #pragma unroll
        for(int j=0;j<4;j++) bfr[j] = *(const short8*)(bBase + j*16*LDA + ks*32);
        #pragma unroll
        for(int i=0;i<4;i++)
            #pragma unroll
            for(int j=0;j<4;j++)
                acc[i][j] = __builtin_amdgcn_mfma_f32_16x16x32_bf16(afr[i], bfr[j], acc[i][j], 0,0,0);
    }

    // ---- softmax statistics ----
    float h1f=(float)h1I[0], w1f=(float)w1I[0], h2f=(float)h2I[0], w2f=(float)w2I[0];
    float sx2 = 0.5f*(w2f-1.0f), sy2 = 0.5f*(h2f-1.0f);   // rows weight coord2 (denorm h2/w2)
    float sx1 = 0.5f*(w1f-1.0f), sy1 = 0.5f*(h1f-1.0f);   // cols weight coord1 (denorm h1/w1)

    float cx2[4], cy2[4], cxx2[4], cyy2[4];
    #pragma unroll
    for(int j=0;j<4;j++){
        int ml = wc*64 + j*16 + lr;
        float cnx = cn2s[ml*2+0], cny = cn2s[ml*2+1];
        cx2[j] = (cnx+1.f)*sx2; cy2[j] = (cny+1.f)*sy2;
        cxx2[j] = cnx*cnx; cyy2[j] = cny*cny;
    }
    float colA[4][5] = {};
    #pragma unroll
    for(int i=0;i<4;i++){
        #pragma unroll
        for(int r=0;r<4;r++){
            int nl = wr*64 + i*16 + lh*4 + r;
            float cnx1 = cn1s[nl*2+0], cny1 = cn1s[nl*2+1];
            float cx1=(cnx1+1.f)*sx1, cy1=(cny1+1.f)*sy1;
            float cxx1=cnx1*cnx1, cyy1=cny1*cny1;
            float rs=0.f, rax=0.f, ray=0.f, raxx=0.f, rayy=0.f;
            #pragma unroll
            for(int j=0;j<4;j++){
                float wgt = __expf(fmaf(TT, acc[i][j][r], -16.0f));
                rs += wgt;
                rax  = fmaf(wgt, cx2[j],  rax);
                ray  = fmaf(wgt, cy2[j],  ray);
                raxx = fmaf(wgt, cxx2[j], raxx);
                rayy = fmaf(wgt, cyy2[j], rayy);
                colA[j][0] += wgt;
                colA[j][1] = fmaf(wgt, cx1,  colA[j][1]);
                colA[j][2] = fmaf(wgt, cy1,  colA[j][2]);
                colA[j][3] = fmaf(wgt, cxx1, colA[j][3]);
                colA[j][4] = fmaf(wgt, cyy1, colA[j][4]);
            }
            #pragma unroll
            for(int msk=1; msk<16; msk<<=1){
                rs   += __shfl_xor(rs,   msk);
                rax  += __shfl_xor(rax,  msk);
                ray  += __shfl_xor(ray,  msk);
                raxx += __shfl_xor(raxx, msk);
                rayy += __shfl_xor(rayy, msk);
            }
            if(lr==0){
                float* p = rowPart[wc][nl];
                p[0]=rs; p[1]=rax; p[2]=ray; p[3]=raxx; p[4]=rayy;
            }
        }
    }
    #pragma unroll
    for(int j=0;j<4;j++){
        #pragma unroll
        for(int msk=16; msk<64; msk<<=1){
            #pragma unroll
            for(int c=0;c<5;c++) colA[j][c] += __shfl_xor(colA[j][c], msk);
        }
        if(lh==0){
            int ml = wc*64 + j*16 + lr;
            float* p = colPart[wr][ml];
            #pragma unroll
            for(int c=0;c<5;c++) p[c] = colA[j][c];
        }
    }
    __syncthreads();

    if(tid < 128){
        float* o = wsRow + (((size_t)b*NN + n0 + tid)*NTILE + mt)*5;
        #pragma unroll
        for(int c=0;c<5;c++) o[c] = rowPart[0][tid][c] + rowPart[1][tid][c];
    } else {
        int t = tid - 128;
        float* o = wsCol + (((size_t)b*NN + m0 + t)*NTILE + nt)*5;
        #pragma unroll
        for(int c=0;c<5;c++) o[c] = colPart[0][t][c] + colPart[1][t][c];
    }
}

// Combine NTILE partials per point, finalize g / gn / std for both directions.
__global__ __launch_bounds__(256) void k_red(
        const float* __restrict__ wsRow, const float* __restrict__ wsCol,
        float* __restrict__ o_g1, float* __restrict__ o_g1n, float* __restrict__ o_std1,
        float* __restrict__ o_g2, float* __restrict__ o_g2n, float* __restrict__ o_std2,
        const int* __restrict__ h1I, const int* __restrict__ w1I,
        const int* __restrict__ h2I, const int* __restrict__ w2I){
    int p = blockIdx.x*256 + threadIdx.x;
    if(p >= 2*BB*NN) return;
    int dir = p / (BB*NN);
    int i   = p % (BB*NN);
    const float* src = (dir ? wsCol : wsRow) + (size_t)i*NTILE*5;
    float S=0.f, AX=0.f, AY=0.f, AXX=0.f, AYY=0.f;
    for(int t=0;t<NTILE;t++){
        S   += src[t*5+0];
        AX  += src[t*5+1];
        AY  += src[t*5+2];
        AXX += src[t*5+3];
        AYY += src[t*5+4];
    }
    float hf = dir ? (float)h1I[0] : (float)h2I[0];
    float wf = dir ? (float)w1I[0] : (float)w2I[0];
    float gx = AX/S, gy = AY/S;
    float gnx = gx * (2.0f/(wf-1.0f)) - 1.0f;
    float gny = gy * (2.0f/(hf-1.0f)) - 1.0f;
    float vx = AXX/S - gnx*gnx;
    float vy = AYY/S - gny*gny;
    float sd = sqrtf(fmaxf(vx,1e-6f)) + sqrtf(fmaxf(vy,1e-6f));
    float* oG  = dir ? o_g2  : o_g1;
    float* oGn = dir ? o_g2n : o_g1n;
    float* oSd = dir ? o_std2: o_std1;
    oG[(size_t)i*2+0]=gx;  oG[(size_t)i*2+1]=gy;
    oGn[(size_t)i*2+0]=gnx; oGn[(size_t)i*2+1]=gny;
    oSd[i]=sd;
}

// Window refinement (unchanged except bf16 query feature).
__global__ __launch_bounds__(128) void k_win(
        const __hip_bfloat16* __restrict__ fQ, const float* __restrict__ fmapT,
        const float* __restrict__ center,
        float* __restrict__ outW, float* __restrict__ outStd,
        const int* __restrict__ hI, const int* __restrict__ wI){
    int bn = blockIdx.x;
    int b = bn / NN;
    int tid = threadIdx.x;
    __shared__ __align__(16) float fq[CC];
    fq[tid] = __bfloat162float(fQ[(size_t)bn*CC + tid]);
    float gx = center[(size_t)bn*2+0], gy = center[(size_t)bn*2+1];
    __syncthreads();
    int s = (tid < SS) ? tid : (SS-1);
    float wcx = gx + (-0.125f + 0.03125f*(float)(s % 9));
    float wcy = gy + (-0.125f + 0.03125f*(float)(s / 9));
    int x0,x1,y0,y1; float wx,wy;
    bsetup(wcx, WW, x0,x1,wx);
    bsetup(wcy, HH, y0,y1,wy);
    const float4* p00 = (const float4*)(fmapT + ((size_t)(b*HW) + y0*WW + x0)*CC);
    const float4* p01 = (const float4*)(fmapT + ((size_t)(b*HW) + y0*WW + x1)*CC);
    const float4* p10 = (const float4*)(fmapT + ((size_t)(b*HW) + y1*WW + x0)*CC);
    const float4* p11 = (const float4*)(fmapT + ((size_t)(b*HW) + y1*WW + x1)*CC);
    float w00=(1.f-wx)*(1.f-wy), w01=wx*(1.f-wy), w10=(1.f-wx)*wy, w11=wx*wy;
    float d = 0.f;
    #pragma unroll
    for(int cq=0; cq<CC/4; cq++){
        float4 a = ((const float4*)fq)[cq];
        float4 v00 = p00[cq], v01 = p01[cq], v10 = p10[cq], v11 = p11[cq];
        d += a.x*(w00*v00.x + w01*v01.x + w10*v10.x + w11*v11.x);
        d += a.y*(w00*v00.y + w01*v01.y + w10*v10.y + w11*v11.y);
        d += a.z*(w00*v00.z + w01*v01.z + w10*v10.z + w11*v11.z);
        d += a.w*(w00*v00.w + w01*v01.w + w10*v10.w + w11*v11.w);
    }
    float logit = (tid < SS) ? d : -INFINITY;
    float M = logit;
    #pragma unroll
    for(int off=32; off>0; off>>=1) M = fmaxf(M, __shfl_down(M, off));
    __shared__ float mred[2];
    if((tid & 63) == 0) mred[tid>>6] = M;
    __syncthreads();
    M = fmaxf(mred[0], mred[1]);
    float w = (tid < SS) ? __expf(logit - M) : 0.f;
    float v0=w, v1=w*wcx, v2=w*wcy, v3=w*wcx*wcx, v4=w*wcy*wcy;
    #pragma unroll
    for(int off=32; off>0; off>>=1){
        v0 += __shfl_down(v0, off);
        v1 += __shfl_down(v1, off);
        v2 += __shfl_down(v2, off);
        v3 += __shfl_down(v3, off);
        v4 += __shfl_down(v4, off);
    }
    __shared__ float sred[2][5];
    if((tid&63)==0){ int wv=tid>>6; sred[wv][0]=v0; sred[wv][1]=v1; sred[wv][2]=v2; sred[wv][3]=v3; sred[wv][4]=v4; }
    __syncthreads();
    if(tid==0){
        float S = sred[0][0]+sred[1][0];
        float ex = (sred[0][1]+sred[1][1])/S;
        float ey = (sred[0][2]+sred[1][2])/S;
        float vx = (sred[0][3]+sred[1][3])/S - ex*ex;
        float vy = (sred[0][4]+sred[1][4])/S - ey*ey;
        float sd = sqrtf(fmaxf(vx,1e-6f)) + sqrtf(fmaxf(vy,1e-6f));
        float h = (float)hI[0], wimg = (float)wI[0];
        outW[(size_t)bn*2+0] = (ex+1.0f)*0.5f*(wimg-1.0f);
        outW[(size_t)bn*2+1] = (ey+1.0f)*0.5f*(h-1.0f);
        outStd[bn] = sd;
    }
}

__global__ void k_ones(float* __restrict__ p, int n){
    int i = blockIdx.x*256 + threadIdx.x;
    if(i < n) p[i] = 1.0f;
}

extern "C" void kernel_launch(void* const* d_in, const int* in_sizes, int n_in,
                              void* d_out, int out_size, void* d_ws, size_t ws_size,
                              hipStream_t stream){
    const float* xf1 = (const float*)d_in[0];
    const float* xf2 = (const float*)d_in[1];
    const float* c1n = (const float*)d_in[2];
    const float* c2n = (const float*)d_in[3];
    const int* h1 = (const int*)d_in[4];
    const int* w1 = (const int*)d_in[5];
    const int* h2 = (const int*)d_in[6];
    const int* w2 = (const int*)d_in[7];
    float* out = (float*)d_out;
    float* ws = (float*)d_ws;

    float* xf1t = ws;                                   // B*HW*C f32
    float* xf2t = xf1t + (size_t)BB*HW*CC;
    __hip_bfloat16* f1b = (__hip_bfloat16*)(xf2t + (size_t)BB*HW*CC);   // B*N*C bf16
    __hip_bfloat16* f2b = f1b + (size_t)BB*NN*CC;
    float* wsRow = (float*)(f2b + (size_t)BB*NN*CC);    // B*N*NTILE*5 f32
    float* wsCol = wsRow + (size_t)BB*NN*NTILE*5;

    float* o_coord1 = out + 0;
    float* o_coord2 = out + 12288;
    float* o_g1     = out + 24576;
    float* o_g2     = out + 36864;
    float* o_w1     = out + 49152;
    float* o_w2     = out + 61440;
    float* o_g1n    = out + 73728;
    float* o_g2n    = out + 86016;
    float* o_std1   = out + 98304;
    float* o_std2   = out + 104448;
    float* o_wstd1  = out + 110592;
    float* o_wstd2  = out + 116736;
    float* o_valid  = out + 122880;

    hipLaunchKernelGGL(k_normT, dim3(2*BB*HW), dim3(128), 0, stream, xf1, xf2, xf1t, xf2t);
    hipLaunchKernelGGL(k_feats, dim3(BB*NN), dim3(128), 0, stream, xf1, c1n, f1b, o_coord1, h1, w1);
    hipLaunchKernelGGL(k_feats, dim3(BB*NN), dim3(128), 0, stream, xf2, c2n, f2b, o_coord2, h2, w2);
    hipLaunchKernelGGL(k_corr, dim3(BB*NTILE*NTILE), dim3(256), 0, stream,
                       f1b, f2b, c1n, c2n, wsRow, wsCol, h1, w1, h2, w2);
    hipLaunchKernelGGL(k_red, dim3((2*BB*NN+255)/256), dim3(256), 0, stream,
                       wsRow, wsCol, o_g1, o_g1n, o_std1, o_g2, o_g2n, o_std2, h1, w1, h2, w2);
    hipLaunchKernelGGL(k_win, dim3(BB*NN), dim3(128), 0, stream, f1b, xf2t, o_g1n, o_w1, o_wstd1, h2, w2);
    hipLaunchKernelGGL(k_win, dim3(BB*NN), dim3(128), 0, stream, f2b, xf1t, o_g2n, o_w2, o_wstd2, h1, w1);
    hipLaunchKernelGGL(k_ones, dim3((2*BB*NN+255)/256), dim3(256), 0, stream, o_valid, 2*BB*NN);
}

// Round 3
// 211.919 us; speedup vs baseline: 8.9522x; 1.6301x over previous
//
#include <hip/hip_runtime.h>
#include <hip/hip_bf16.h>
#include <math.h>

#define BB 2
#define CC 128
#define HH 60
#define WW 80
#define NN 3072
#define TT 16.0f
#define SS 81
#define HW (HH*WW)
#define NTILE 24   // 3072/128
#define LDA 136    // 128 + 8 bf16 pad -> 272B row stride, 16B aligned, 2-way bank (free)
#define XN 12
#define YN 10

typedef __attribute__((ext_vector_type(8))) short short8;
typedef __attribute__((ext_vector_type(4))) float f32x4;

__device__ __forceinline__ void bsetup(float cn, int L, int& i0, int& i1, float& w){
    float x = (cn + 1.0f) * 0.5f * (float)(L - 1);
    float x0 = floorf(x);
    w = x - x0;
    int xi = (int)x0;
    i0 = xi < 0 ? 0 : (xi > L - 1 ? L - 1 : xi);
    i1 = (i0 + 1 > L - 1) ? L - 1 : (i0 + 1);
}

// Per-pixel L2-norm over C, scale by T, write transposed (B,H,W,C).
__global__ __launch_bounds__(128) void k_normT(const float* __restrict__ xf1, const float* __restrict__ xf2,
                        float* __restrict__ xf1t, float* __restrict__ xf2t){
    int idx = blockIdx.x;
    int map = idx / (BB*HW);
    int pix = idx % (BB*HW);
    const float* src = map ? xf2 : xf1;
    float* dst = map ? xf2t : xf1t;
    int b = pix / HW, hw = pix % HW;
    int c = threadIdx.x;
    float v = src[(size_t)(b*CC + c)*HW + hw];
    __shared__ float red[128];
    red[c] = v*v;
    __syncthreads();
    #pragma unroll
    for(int s=64; s>0; s>>=1){ if(c<s) red[c]+=red[c+s]; __syncthreads(); }
    float nrm = TT / sqrtf(red[0] + 1e-12f);
    dst[(size_t)pix*CC + c] = v * nrm;
}

// Bilinear sample raw map at coords, L2-normalize over C -> bf16 features; also denormed coords.
__global__ __launch_bounds__(128) void k_feats(
        const float* __restrict__ xf, const float* __restrict__ cn,
        __hip_bfloat16* __restrict__ fOutB, float* __restrict__ coordOut,
        const int* __restrict__ hI, const int* __restrict__ wI){
    int bn = blockIdx.x;
    int b = bn / NN;
    int c = threadIdx.x;
    float cnx = cn[(size_t)bn*2+0], cny = cn[(size_t)bn*2+1];
    int x0,x1,y0,y1; float wx,wy;
    bsetup(cnx, WW, x0,x1,wx);
    bsetup(cny, HH, y0,y1,wy);
    const float* base = xf + ((size_t)b*CC + c)*HW;
    float f00 = base[y0*WW+x0], f01 = base[y0*WW+x1];
    float f10 = base[y1*WW+x0], f11 = base[y1*WW+x1];
    float f = f00*(1.f-wx)*(1.f-wy) + f01*wx*(1.f-wy) + f10*(1.f-wx)*wy + f11*wx*wy;
    __shared__ float red[128];
    red[c] = f*f; __syncthreads();
    #pragma unroll
    for(int st=64; st>0; st>>=1){ if(c<st) red[c]+=red[c+st]; __syncthreads(); }
    float nrm = sqrtf(red[0] + 1e-12f);
    fOutB[(size_t)bn*CC + c] = __float2bfloat16(f / nrm);
    if(c==0){
        float h=(float)hI[0], w=(float)wI[0];
        coordOut[(size_t)bn*2+0] = (cnx+1.0f)*0.5f*(w-1.0f);
        coordOut[(size_t)bn*2+1] = (cny+1.0f)*0.5f*(h-1.0f);
    }
}

// Fused correlation: ONE bf16-MFMA GEMM pass producing BOTH row (p12) and col (p21)
// partial softmax statistics.
__global__ __launch_bounds__(256,2) void k_corr(
        const __hip_bfloat16* __restrict__ f1b, const __hip_bfloat16* __restrict__ f2b,
        const float* __restrict__ c1n, const float* __restrict__ c2n,
        float* __restrict__ wsRow, float* __restrict__ wsCol,
        const int* __restrict__ h1I, const int* __restrict__ w1I,
        const int* __restrict__ h2I, const int* __restrict__ w2I){
    int blk = blockIdx.x;
    int b   = blk / (NTILE*NTILE);
    int rem = blk % (NTILE*NTILE);
    int nt = rem / NTILE, mt = rem % NTILE;
    int n0 = nt*128, m0 = mt*128;
    int tid = threadIdx.x;
    int lane = tid & 63, wid = tid >> 6;
    int wr = wid >> 1, wc = wid & 1;
    int lr = lane & 15, lh = lane >> 4;

    __shared__ __align__(16) unsigned short As[128*LDA];
    __shared__ __align__(16) unsigned short Bs[128*LDA];
    __shared__ float cn1s[128*2];
    __shared__ float cn2s[128*2];
    __shared__ float rowPart[2][128][5];
    __shared__ float colPart[2][128][5];

    {
        const unsigned short* gA = (const unsigned short*)f1b + ((size_t)b*NN + n0)*CC;
        const unsigned short* gB = (const unsigned short*)f2b + ((size_t)b*NN + m0)*CC;
        #pragma unroll
        for(int it=0; it<8; ++it){
            int idx = tid + it*256;
            int r = idx >> 4, q = idx & 15;
            *(uint4*)(As + r*LDA + q*8) = *(const uint4*)(gA + r*CC + q*8);
            *(uint4*)(Bs + r*LDA + q*8) = *(const uint4*)(gB + r*CC + q*8);
        }
        if(tid < 128){
            cn1s[tid*2+0] = c1n[((size_t)b*NN + n0 + tid)*2+0];
            cn1s[tid*2+1] = c1n[((size_t)b*NN + n0 + tid)*2+1];
        } else {
            int t = tid - 128;
            cn2s[t*2+0] = c2n[((size_t)b*NN + m0 + t)*2+0];
            cn2s[t*2+1] = c2n[((size_t)b*NN + m0 + t)*2+1];
        }
    }
    __syncthreads();

    f32x4 acc[4][4] = {};
    const unsigned short* aBase = As + (wr*64 + lr)*LDA + lh*8;
    const unsigned short* bBase = Bs + (wc*64 + lr)*LDA + lh*8;
    #pragma unroll
    for(int ks=0; ks<4; ++ks){
        short8 afr[4], bfr[4];
        #pragma unroll
        for(int i=0;i<4;i++) afr[i] = *(const short8*)(aBase + i*16*LDA + ks*32);
        #pragma unroll
        for(int j=0;j<4;j++) bfr[j] = *(const short8*)(bBase + j*16*LDA + ks*32);
        #pragma unroll
        for(int i=0;i<4;i++)
            #pragma unroll
            for(int j=0;j<4;j++)
                acc[i][j] = __builtin_amdgcn_mfma_f32_16x16x32_bf16(afr[i], bfr[j], acc[i][j], 0,0,0);
    }

    float h1f=(float)h1I[0], w1f=(float)w1I[0], h2f=(float)h2I[0], w2f=(float)w2I[0];
    float sx2 = 0.5f*(w2f-1.0f), sy2 = 0.5f*(h2f-1.0f);
    float sx1 = 0.5f*(w1f-1.0f), sy1 = 0.5f*(h1f-1.0f);

    float cx2[4], cy2[4], cxx2[4], cyy2[4];
    #pragma unroll
    for(int j=0;j<4;j++){
        int ml = wc*64 + j*16 + lr;
        float cnx = cn2s[ml*2+0], cny = cn2s[ml*2+1];
        cx2[j] = (cnx+1.f)*sx2; cy2[j] = (cny+1.f)*sy2;
        cxx2[j] = cnx*cnx; cyy2[j] = cny*cny;
    }
    float colA[4][5] = {};
    #pragma unroll
    for(int i=0;i<4;i++){
        #pragma unroll
        for(int r=0;r<4;r++){
            int nl = wr*64 + i*16 + lh*4 + r;
            float cnx1 = cn1s[nl*2+0], cny1 = cn1s[nl*2+1];
            float cx1=(cnx1+1.f)*sx1, cy1=(cny1+1.f)*sy1;
            float cxx1=cnx1*cnx1, cyy1=cny1*cny1;
            float rs=0.f, rax=0.f, ray=0.f, raxx=0.f, rayy=0.f;
            #pragma unroll
            for(int j=0;j<4;j++){
                float wgt = __expf(fmaf(TT, acc[i][j][r], -16.0f));
                rs += wgt;
                rax  = fmaf(wgt, cx2[j],  rax);
                ray  = fmaf(wgt, cy2[j],  ray);
                raxx = fmaf(wgt, cxx2[j], raxx);
                rayy = fmaf(wgt, cyy2[j], rayy);
                colA[j][0] += wgt;
                colA[j][1] = fmaf(wgt, cx1,  colA[j][1]);
                colA[j][2] = fmaf(wgt, cy1,  colA[j][2]);
                colA[j][3] = fmaf(wgt, cxx1, colA[j][3]);
                colA[j][4] = fmaf(wgt, cyy1, colA[j][4]);
            }
            #pragma unroll
            for(int msk=1; msk<16; msk<<=1){
                rs   += __shfl_xor(rs,   msk);
                rax  += __shfl_xor(rax,  msk);
                ray  += __shfl_xor(ray,  msk);
                raxx += __shfl_xor(raxx, msk);
                rayy += __shfl_xor(rayy, msk);
            }
            if(lr==0){
                float* p = rowPart[wc][nl];
                p[0]=rs; p[1]=rax; p[2]=ray; p[3]=raxx; p[4]=rayy;
            }
        }
    }
    #pragma unroll
    for(int j=0;j<4;j++){
        #pragma unroll
        for(int msk=16; msk<64; msk<<=1){
            #pragma unroll
            for(int c=0;c<5;c++) colA[j][c] += __shfl_xor(colA[j][c], msk);
        }
        if(lh==0){
            int ml = wc*64 + j*16 + lr;
            float* p = colPart[wr][ml];
            #pragma unroll
            for(int c=0;c<5;c++) p[c] = colA[j][c];
        }
    }
    __syncthreads();

    if(tid < 128){
        float* o = wsRow + (((size_t)b*NN + n0 + tid)*NTILE + mt)*5;
        #pragma unroll
        for(int c=0;c<5;c++) o[c] = rowPart[0][tid][c] + rowPart[1][tid][c];
    } else {
        int t = tid - 128;
        float* o = wsCol + (((size_t)b*NN + m0 + t)*NTILE + nt)*5;
        #pragma unroll
        for(int c=0;c<5;c++) o[c] = colPart[0][t][c] + colPart[1][t][c];
    }
}

// Combine NTILE partials per point, finalize g / gn / std for both directions.
__global__ __launch_bounds__(256) void k_red(
        const float* __restrict__ wsRow, const float* __restrict__ wsCol,
        float* __restrict__ o_g1, float* __restrict__ o_g1n, float* __restrict__ o_std1,
        float* __restrict__ o_g2, float* __restrict__ o_g2n, float* __restrict__ o_std2,
        const int* __restrict__ h1I, const int* __restrict__ w1I,
        const int* __restrict__ h2I, const int* __restrict__ w2I){
    int p = blockIdx.x*256 + threadIdx.x;
    if(p >= 2*BB*NN) return;
    int dir = p / (BB*NN);
    int i   = p % (BB*NN);
    const float* src = (dir ? wsCol : wsRow) + (size_t)i*NTILE*5;
    float S=0.f, AX=0.f, AY=0.f, AXX=0.f, AYY=0.f;
    for(int t=0;t<NTILE;t++){
        S   += src[t*5+0];
        AX  += src[t*5+1];
        AY  += src[t*5+2];
        AXX += src[t*5+3];
        AYY += src[t*5+4];
    }
    float hf = dir ? (float)h1I[0] : (float)h2I[0];
    float wf = dir ? (float)w1I[0] : (float)w2I[0];
    float gx = AX/S, gy = AY/S;
    float gnx = gx * (2.0f/(wf-1.0f)) - 1.0f;
    float gny = gy * (2.0f/(hf-1.0f)) - 1.0f;
    float vx = AXX/S - gnx*gnx;
    float vy = AYY/S - gny*gny;
    float sd = sqrtf(fmaxf(vx,1e-6f)) + sqrtf(fmaxf(vy,1e-6f));
    float* oG  = dir ? o_g2  : o_g1;
    float* oGn = dir ? o_g2n : o_g1n;
    float* oSd = dir ? o_std2: o_std1;
    oG[(size_t)i*2+0]=gx;  oG[(size_t)i*2+1]=gy;
    oGn[(size_t)i*2+0]=gnx; oGn[(size_t)i*2+1]=gny;
    oSd[i]=sd;
}

// Window refinement, restructured:
// Phase 1: the 81 samples' bilinear corners lie in a <=12x10 pixel grid starting at
// (xb,yb)=floor-clip of the first sample. dot(fq, bilinear(f)) == bilinear(dot(fq,f)),
// so compute one 128-ch dot per distinct pixel: wave-parallel, lane=2 channels,
// fully coalesced 512B row loads + shfl_xor reduce. 4 waves x 30 pixels.
// Phase 2: 81 threads combine 4 LDS dots with bilinear weights -> softmax -> moments.
// Both directions in one launch (dir = blockIdx.x / (B*N)).
__global__ __launch_bounds__(256) void k_win2(
        const __hip_bfloat16* __restrict__ f1b, const __hip_bfloat16* __restrict__ f2b,
        const float* __restrict__ xf1t, const float* __restrict__ xf2t,
        const float* __restrict__ g1n, const float* __restrict__ g2n,
        float* __restrict__ o_w1, float* __restrict__ o_wstd1,
        float* __restrict__ o_w2, float* __restrict__ o_wstd2,
        const int* __restrict__ h1I, const int* __restrict__ w1I,
        const int* __restrict__ h2I, const int* __restrict__ w2I){
    int gid = blockIdx.x;
    int dir = gid / (BB*NN);
    int bn  = gid % (BB*NN);
    int b   = bn / NN;
    const __hip_bfloat16* fQ = dir ? f2b : f1b;
    const float* fmapT       = dir ? xf1t : xf2t;
    const float* center      = dir ? g2n  : g1n;
    const int* hI            = dir ? h1I  : h2I;
    const int* wI            = dir ? w1I  : w2I;
    float* outW              = dir ? o_w2 : o_w1;
    float* outStd            = dir ? o_wstd2 : o_wstd1;

    int tid = threadIdx.x;
    int lane = tid & 63, wid = tid >> 6;

    float gx = center[(size_t)bn*2+0], gy = center[(size_t)bn*2+1];
    int xb, yb;
    {   int t1; float tw;
        bsetup(gx - 0.125f, WW, xb, t1, tw);
        bsetup(gy - 0.125f, HH, yb, t1, tw);
    }

    // lane's two channels of the query feature (bf16 pair -> 2 floats)
    unsigned int uq = ((const unsigned int*)(fQ + (size_t)bn*CC))[lane];
    float fqx = __uint_as_float(uq << 16);
    float fqy = __uint_as_float(uq & 0xffff0000u);

    __shared__ float dl[XN*YN];
    const float* base = fmapT + (size_t)b*HW*CC;
    #pragma unroll 2
    for(int p = wid; p < XN*YN; p += 4){
        int ky = p / XN, kx = p - ky*XN;
        int py = yb + ky; if(py > HH-1) py = HH-1;
        int px = xb + kx; if(px > WW-1) px = WW-1;
        float2 v = ((const float2*)(base + ((size_t)(py*WW + px))*CC))[lane];
        float s = fqx*v.x + fqy*v.y;
        #pragma unroll
        for(int m=1; m<64; m<<=1) s += __shfl_xor(s, m);
        if(lane==0) dl[p] = s;
    }
    __syncthreads();

    float logit = -INFINITY, wcx = 0.f, wcy = 0.f;
    if(tid < SS){
        int i = tid % 9, j = tid / 9;
        wcx = gx + (-0.125f + 0.03125f*(float)i);
        wcy = gy + (-0.125f + 0.03125f*(float)j);
        int x0,x1,y0,y1; float wx,wy;
        bsetup(wcx, WW, x0,x1,wx);
        bsetup(wcy, HH, y0,y1,wy);
        int r0 = (y0-yb)*XN - xb, r1 = (y1-yb)*XN - xb;
        float d00=dl[r0+x0], d01=dl[r0+x1], d10=dl[r1+x0], d11=dl[r1+x1];
        logit = d00*(1.f-wx)*(1.f-wy) + d01*wx*(1.f-wy) + d10*(1.f-wx)*wy + d11*wx*wy;
    }

    float M = logit;
    #pragma unroll
    for(int m=1; m<64; m<<=1) M = fmaxf(M, __shfl_xor(M, m));
    __shared__ float mred[4];
    if(lane==0) mred[wid] = M;
    __syncthreads();
    M = fmaxf(fmaxf(mred[0],mred[1]), fmaxf(mred[2],mred[3]));

    float w = (tid < SS) ? __expf(logit - M) : 0.f;
    float v0=w, v1=w*wcx, v2=w*wcy, v3=w*wcx*wcx, v4=w*wcy*wcy;
    #pragma unroll
    for(int m=1; m<64; m<<=1){
        v0 += __shfl_xor(v0, m);
        v1 += __shfl_xor(v1, m);
        v2 += __shfl_xor(v2, m);
        v3 += __shfl_xor(v3, m);
        v4 += __shfl_xor(v4, m);
    }
    __shared__ float sred[4][5];
    if(lane==0){ sred[wid][0]=v0; sred[wid][1]=v1; sred[wid][2]=v2; sred[wid][3]=v3; sred[wid][4]=v4; }
    __syncthreads();
    if(tid==0){
        float S  = sred[0][0]+sred[1][0]+sred[2][0]+sred[3][0];
        float ex = (sred[0][1]+sred[1][1]+sred[2][1]+sred[3][1])/S;
        float ey = (sred[0][2]+sred[1][2]+sred[2][2]+sred[3][2])/S;
        float vx = (sred[0][3]+sred[1][3]+sred[2][3]+sred[3][3])/S - ex*ex;
        float vy = (sred[0][4]+sred[1][4]+sred[2][4]+sred[3][4])/S - ey*ey;
        float sd = sqrtf(fmaxf(vx,1e-6f)) + sqrtf(fmaxf(vy,1e-6f));
        float h = (float)hI[0], wimg = (float)wI[0];
        outW[(size_t)bn*2+0] = (ex+1.0f)*0.5f*(wimg-1.0f);
        outW[(size_t)bn*2+1] = (ey+1.0f)*0.5f*(h-1.0f);
        outStd[bn] = sd;
    }
}

__global__ void k_ones(float* __restrict__ p, int n){
    int i = blockIdx.x*256 + threadIdx.x;
    if(i < n) p[i] = 1.0f;
}

extern "C" void kernel_launch(void* const* d_in, const int* in_sizes, int n_in,
                              void* d_out, int out_size, void* d_ws, size_t ws_size,
                              hipStream_t stream){
    const float* xf1 = (const float*)d_in[0];
    const float* xf2 = (const float*)d_in[1];
    const float* c1n = (const float*)d_in[2];
    const float* c2n = (const float*)d_in[3];
    const int* h1 = (const int*)d_in[4];
    const int* w1 = (const int*)d_in[5];
    const int* h2 = (const int*)d_in[6];
    const int* w2 = (const int*)d_in[7];
    float* out = (float*)d_out;
    float* ws = (float*)d_ws;

    float* xf1t = ws;                                   // B*HW*C f32
    float* xf2t = xf1t + (size_t)BB*HW*CC;
    __hip_bfloat16* f1b = (__hip_bfloat16*)(xf2t + (size_t)BB*HW*CC);   // B*N*C bf16
    __hip_bfloat16* f2b = f1b + (size_t)BB*NN*CC;
    float* wsRow = (float*)(f2b + (size_t)BB*NN*CC);    // B*N*NTILE*5 f32
    float* wsCol = wsRow + (size_t)BB*NN*NTILE*5;

    float* o_coord1 = out + 0;
    float* o_coord2 = out + 12288;
    float* o_g1     = out + 24576;
    float* o_g2     = out + 36864;
    float* o_w1     = out + 49152;
    float* o_w2     = out + 61440;
    float* o_g1n    = out + 73728;
    float* o_g2n    = out + 86016;
    float* o_std1   = out + 98304;
    float* o_std2   = out + 104448;
    float* o_wstd1  = out + 110592;
    float* o_wstd2  = out + 116736;
    float* o_valid  = out + 122880;

    hipLaunchKernelGGL(k_normT, dim3(2*BB*HW), dim3(128), 0, stream, xf1, xf2, xf1t, xf2t);
    hipLaunchKernelGGL(k_feats, dim3(BB*NN), dim3(128), 0, stream, xf1, c1n, f1b, o_coord1, h1, w1);
    hipLaunchKernelGGL(k_feats, dim3(BB*NN), dim3(128), 0, stream, xf2, c2n, f2b, o_coord2, h2, w2);
    hipLaunchKernelGGL(k_corr, dim3(BB*NTILE*NTILE), dim3(256), 0, stream,
                       f1b, f2b, c1n, c2n, wsRow, wsCol, h1, w1, h2, w2);
    hipLaunchKernelGGL(k_red, dim3((2*BB*NN+255)/256), dim3(256), 0, stream,
                       wsRow, wsCol, o_g1, o_g1n, o_std1, o_g2, o_g2n, o_std2, h1, w1, h2, w2);
    hipLaunchKernelGGL(k_win2, dim3(2*BB*NN), dim3(256), 0, stream,
                       f1b, f2b, xf1t, xf2t, o_g1n, o_g2n,
                       o_w1, o_wstd1, o_w2, o_wstd2, h1, w1, h2, w2);
    hipLaunchKernelGGL(k_ones, dim3((2*BB*NN+255)/256), dim3(256), 0, stream, o_valid, 2*BB*NN);
}

// Round 4
// 129.179 us; speedup vs baseline: 14.6860x; 1.6405x over previous
//
#include <hip/hip_runtime.h>
#include <hip/hip_bf16.h>
#include <math.h>

#define BB 2
#define CC 128
#define HH 60
#define WW 80
#define NN 3072
#define TT 16.0f
#define SS 81
#define HW (HH*WW)
#define NTILE 24   // 3072/128
#define LDA 136    // 128 + 8 bf16 pad -> 272B row stride, 16B aligned, 2-way bank (free)
#define XN 12
#define YN 10

typedef __attribute__((ext_vector_type(8))) short short8;
typedef __attribute__((ext_vector_type(4))) float f32x4;

__device__ __forceinline__ void bsetup(float cn, int L, int& i0, int& i1, float& w){
    float x = (cn + 1.0f) * 0.5f * (float)(L - 1);
    float x0 = floorf(x);
    w = x - x0;
    int xi = (int)x0;
    i0 = xi < 0 ? 0 : (xi > L - 1 ? L - 1 : xi);
    i1 = (i0 + 1 > L - 1) ? L - 1 : (i0 + 1);
}

// Per-pixel L2-norm over C, scale by T, write transposed (B,H,W,C).
__global__ __launch_bounds__(128) void k_normT(const float* __restrict__ xf1, const float* __restrict__ xf2,
                        float* __restrict__ xf1t, float* __restrict__ xf2t){
    int idx = blockIdx.x;
    int map = idx / (BB*HW);
    int pix = idx % (BB*HW);
    const float* src = map ? xf2 : xf1;
    float* dst = map ? xf2t : xf1t;
    int b = pix / HW, hw = pix % HW;
    int c = threadIdx.x;
    float v = src[(size_t)(b*CC + c)*HW + hw];
    __shared__ float red[128];
    red[c] = v*v;
    __syncthreads();
    #pragma unroll
    for(int s=64; s>0; s>>=1){ if(c<s) red[c]+=red[c+s]; __syncthreads(); }
    float nrm = TT / sqrtf(red[0] + 1e-12f);
    dst[(size_t)pix*CC + c] = v * nrm;
}

// Bilinear sample raw map at coords, L2-normalize over C -> bf16 features; also denormed
// coords. Both directions in one launch.
__global__ __launch_bounds__(128) void k_feats(
        const float* __restrict__ xf1, const float* __restrict__ xf2,
        const float* __restrict__ c1n, const float* __restrict__ c2n,
        __hip_bfloat16* __restrict__ f1b, __hip_bfloat16* __restrict__ f2b,
        float* __restrict__ o_coord1, float* __restrict__ o_coord2,
        const int* __restrict__ h1I, const int* __restrict__ w1I,
        const int* __restrict__ h2I, const int* __restrict__ w2I){
    int gid = blockIdx.x;
    int dir = gid / (BB*NN);
    int bn  = gid % (BB*NN);
    int b = bn / NN;
    const float* xf = dir ? xf2 : xf1;
    const float* cn = dir ? c2n : c1n;
    __hip_bfloat16* fOutB = dir ? f2b : f1b;
    float* coordOut = dir ? o_coord2 : o_coord1;
    const int* hI = dir ? h2I : h1I;
    const int* wI = dir ? w2I : w1I;

    int c = threadIdx.x;
    float cnx = cn[(size_t)bn*2+0], cny = cn[(size_t)bn*2+1];
    int x0,x1,y0,y1; float wx,wy;
    bsetup(cnx, WW, x0,x1,wx);
    bsetup(cny, HH, y0,y1,wy);
    const float* base = xf + ((size_t)b*CC + c)*HW;
    float f00 = base[y0*WW+x0], f01 = base[y0*WW+x1];
    float f10 = base[y1*WW+x0], f11 = base[y1*WW+x1];
    float f = f00*(1.f-wx)*(1.f-wy) + f01*wx*(1.f-wy) + f10*(1.f-wx)*wy + f11*wx*wy;
    __shared__ float red[128];
    red[c] = f*f; __syncthreads();
    #pragma unroll
    for(int st=64; st>0; st>>=1){ if(c<st) red[c]+=red[c+st]; __syncthreads(); }
    float nrm = sqrtf(red[0] + 1e-12f);
    fOutB[(size_t)bn*CC + c] = __float2bfloat16(f / nrm);
    if(c==0){
        float h=(float)hI[0], w=(float)wI[0];
        coordOut[(size_t)bn*2+0] = (cnx+1.0f)*0.5f*(w-1.0f);
        coordOut[(size_t)bn*2+1] = (cny+1.0f)*0.5f*(h-1.0f);
    }
}

// Fused correlation: ONE bf16-MFMA GEMM pass producing BOTH row (p12) and col (p21)
// partial softmax statistics.
__global__ __launch_bounds__(256,2) void k_corr(
        const __hip_bfloat16* __restrict__ f1b, const __hip_bfloat16* __restrict__ f2b,
        const float* __restrict__ c1n, const float* __restrict__ c2n,
        float* __restrict__ wsRow, float* __restrict__ wsCol,
        const int* __restrict__ h1I, const int* __restrict__ w1I,
        const int* __restrict__ h2I, const int* __restrict__ w2I){
    int blk = blockIdx.x;
    int b   = blk / (NTILE*NTILE);
    int rem = blk % (NTILE*NTILE);
    int nt = rem / NTILE, mt = rem % NTILE;
    int n0 = nt*128, m0 = mt*128;
    int tid = threadIdx.x;
    int lane = tid & 63, wid = tid >> 6;
    int wr = wid >> 1, wc = wid & 1;
    int lr = lane & 15, lh = lane >> 4;

    __shared__ __align__(16) unsigned short As[128*LDA];
    __shared__ __align__(16) unsigned short Bs[128*LDA];
    __shared__ float cn1s[128*2];
    __shared__ float cn2s[128*2];
    __shared__ float rowPart[2][128][5];
    __shared__ float colPart[2][128][5];

    {
        const unsigned short* gA = (const unsigned short*)f1b + ((size_t)b*NN + n0)*CC;
        const unsigned short* gB = (const unsigned short*)f2b + ((size_t)b*NN + m0)*CC;
        #pragma unroll
        for(int it=0; it<8; ++it){
            int idx = tid + it*256;
            int r = idx >> 4, q = idx & 15;
            *(uint4*)(As + r*LDA + q*8) = *(const uint4*)(gA + r*CC + q*8);
            *(uint4*)(Bs + r*LDA + q*8) = *(const uint4*)(gB + r*CC + q*8);
        }
        if(tid < 128){
            cn1s[tid*2+0] = c1n[((size_t)b*NN + n0 + tid)*2+0];
            cn1s[tid*2+1] = c1n[((size_t)b*NN + n0 + tid)*2+1];
        } else {
            int t = tid - 128;
            cn2s[t*2+0] = c2n[((size_t)b*NN + m0 + t)*2+0];
            cn2s[t*2+1] = c2n[((size_t)b*NN + m0 + t)*2+1];
        }
    }
    __syncthreads();

    f32x4 acc[4][4] = {};
    const unsigned short* aBase = As + (wr*64 + lr)*LDA + lh*8;
    const unsigned short* bBase = Bs + (wc*64 + lr)*LDA + lh*8;
    #pragma unroll
    for(int ks=0; ks<4; ++ks){
        short8 afr[4], bfr[4];
        #pragma unroll
        for(int i=0;i<4;i++) afr[i] = *(const short8*)(aBase + i*16*LDA + ks*32);
        #pragma unroll
        for(int j=0;j<4;j++) bfr[j] = *(const short8*)(bBase + j*16*LDA + ks*32);
        #pragma unroll
        for(int i=0;i<4;i++)
            #pragma unroll
            for(int j=0;j<4;j++)
                acc[i][j] = __builtin_amdgcn_mfma_f32_16x16x32_bf16(afr[i], bfr[j], acc[i][j], 0,0,0);
    }

    float h1f=(float)h1I[0], w1f=(float)w1I[0], h2f=(float)h2I[0], w2f=(float)w2I[0];
    float sx2 = 0.5f*(w2f-1.0f), sy2 = 0.5f*(h2f-1.0f);
    float sx1 = 0.5f*(w1f-1.0f), sy1 = 0.5f*(h1f-1.0f);

    float cx2[4], cy2[4], cxx2[4], cyy2[4];
    #pragma unroll
    for(int j=0;j<4;j++){
        int ml = wc*64 + j*16 + lr;
        float cnx = cn2s[ml*2+0], cny = cn2s[ml*2+1];
        cx2[j] = (cnx+1.f)*sx2; cy2[j] = (cny+1.f)*sy2;
        cxx2[j] = cnx*cnx; cyy2[j] = cny*cny;
    }
    float colA[4][5] = {};
    #pragma unroll
    for(int i=0;i<4;i++){
        #pragma unroll
        for(int r=0;r<4;r++){
            int nl = wr*64 + i*16 + lh*4 + r;
            float cnx1 = cn1s[nl*2+0], cny1 = cn1s[nl*2+1];
            float cx1=(cnx1+1.f)*sx1, cy1=(cny1+1.f)*sy1;
            float cxx1=cnx1*cnx1, cyy1=cny1*cny1;
            float rs=0.f, rax=0.f, ray=0.f, raxx=0.f, rayy=0.f;
            #pragma unroll
            for(int j=0;j<4;j++){
                float wgt = __expf(fmaf(TT, acc[i][j][r], -16.0f));
                rs += wgt;
                rax  = fmaf(wgt, cx2[j],  rax);
                ray  = fmaf(wgt, cy2[j],  ray);
                raxx = fmaf(wgt, cxx2[j], raxx);
                rayy = fmaf(wgt, cyy2[j], rayy);
                colA[j][0] += wgt;
                colA[j][1] = fmaf(wgt, cx1,  colA[j][1]);
                colA[j][2] = fmaf(wgt, cy1,  colA[j][2]);
                colA[j][3] = fmaf(wgt, cxx1, colA[j][3]);
                colA[j][4] = fmaf(wgt, cyy1, colA[j][4]);
            }
            #pragma unroll
            for(int msk=1; msk<16; msk<<=1){
                rs   += __shfl_xor(rs,   msk);
                rax  += __shfl_xor(rax,  msk);
                ray  += __shfl_xor(ray,  msk);
                raxx += __shfl_xor(raxx, msk);
                rayy += __shfl_xor(rayy, msk);
            }
            if(lr==0){
                float* p = rowPart[wc][nl];
                p[0]=rs; p[1]=rax; p[2]=ray; p[3]=raxx; p[4]=rayy;
            }
        }
    }
    #pragma unroll
    for(int j=0;j<4;j++){
        #pragma unroll
        for(int msk=16; msk<64; msk<<=1){
            #pragma unroll
            for(int c=0;c<5;c++) colA[j][c] += __shfl_xor(colA[j][c], msk);
        }
        if(lh==0){
            int ml = wc*64 + j*16 + lr;
            float* p = colPart[wr][ml];
            #pragma unroll
            for(int c=0;c<5;c++) p[c] = colA[j][c];
        }
    }
    __syncthreads();

    if(tid < 128){
        float* o = wsRow + (((size_t)b*NN + n0 + tid)*NTILE + mt)*5;
        #pragma unroll
        for(int c=0;c<5;c++) o[c] = rowPart[0][tid][c] + rowPart[1][tid][c];
    } else {
        int t = tid - 128;
        float* o = wsCol + (((size_t)b*NN + m0 + t)*NTILE + nt)*5;
        #pragma unroll
        for(int c=0;c<5;c++) o[c] = colPart[0][t][c] + colPart[1][t][c];
    }
}

// Combine NTILE partials per point, finalize g / gn / std for both directions.
// Also writes the valid flags (1.0) — p maps 1:1 onto the 2*B*N valid entries.
__global__ __launch_bounds__(256) void k_red(
        const float* __restrict__ wsRow, const float* __restrict__ wsCol,
        float* __restrict__ o_g1, float* __restrict__ o_g1n, float* __restrict__ o_std1,
        float* __restrict__ o_g2, float* __restrict__ o_g2n, float* __restrict__ o_std2,
        float* __restrict__ o_valid,
        const int* __restrict__ h1I, const int* __restrict__ w1I,
        const int* __restrict__ h2I, const int* __restrict__ w2I){
    int p = blockIdx.x*256 + threadIdx.x;
    if(p >= 2*BB*NN) return;
    o_valid[p] = 1.0f;
    int dir = p / (BB*NN);
    int i   = p % (BB*NN);
    const float* src = (dir ? wsCol : wsRow) + (size_t)i*NTILE*5;
    float S=0.f, AX=0.f, AY=0.f, AXX=0.f, AYY=0.f;
    for(int t=0;t<NTILE;t++){
        S   += src[t*5+0];
        AX  += src[t*5+1];
        AY  += src[t*5+2];
        AXX += src[t*5+3];
        AYY += src[t*5+4];
    }
    float hf = dir ? (float)h1I[0] : (float)h2I[0];
    float wf = dir ? (float)w1I[0] : (float)w2I[0];
    float gx = AX/S, gy = AY/S;
    float gnx = gx * (2.0f/(wf-1.0f)) - 1.0f;
    float gny = gy * (2.0f/(hf-1.0f)) - 1.0f;
    float vx = AXX/S - gnx*gnx;
    float vy = AYY/S - gny*gny;
    float sd = sqrtf(fmaxf(vx,1e-6f)) + sqrtf(fmaxf(vy,1e-6f));
    float* oG  = dir ? o_g2  : o_g1;
    float* oGn = dir ? o_g2n : o_g1n;
    float* oSd = dir ? o_std2: o_std1;
    oG[(size_t)i*2+0]=gx;  oG[(size_t)i*2+1]=gy;
    oGn[(size_t)i*2+0]=gnx; oGn[(size_t)i*2+1]=gny;
    oSd[i]=sd;
}

// Window refinement. Phase 1: one 128-ch dot per distinct window pixel (<=12x10 grid),
// computed 8 pixels per wave: lane = (sub=pixel, cg=16-channel group); 4x dwordx4 loads
// per lane (512B contiguous per pixel row), 3-step shfl_xor reduce across cg.
// Phase 2: 81 threads do bilinear-combine -> softmax -> moments.
__global__ __launch_bounds__(256) void k_win2(
        const __hip_bfloat16* __restrict__ f1b, const __hip_bfloat16* __restrict__ f2b,
        const float* __restrict__ xf1t, const float* __restrict__ xf2t,
        const float* __restrict__ g1n, const float* __restrict__ g2n,
        float* __restrict__ o_w1, float* __restrict__ o_wstd1,
        float* __restrict__ o_w2, float* __restrict__ o_wstd2,
        const int* __restrict__ h1I, const int* __restrict__ w1I,
        const int* __restrict__ h2I, const int* __restrict__ w2I){
    int gid = blockIdx.x;
    int dir = gid / (BB*NN);
    int bn  = gid % (BB*NN);
    int b   = bn / NN;
    const __hip_bfloat16* fQ = dir ? f2b : f1b;
    const float* fmapT       = dir ? xf1t : xf2t;
    const float* center      = dir ? g2n  : g1n;
    const int* hI            = dir ? h1I  : h2I;
    const int* wI            = dir ? w1I  : w2I;
    float* outW              = dir ? o_w2 : o_w1;
    float* outStd            = dir ? o_wstd2 : o_wstd1;

    int tid = threadIdx.x;
    int lane = tid & 63, wid = tid >> 6;
    int cg  = lane & 7;    // 16-channel group
    int sub = lane >> 3;   // pixel sub-index within wave iter

    float gx = center[(size_t)bn*2+0], gy = center[(size_t)bn*2+1];
    int xb, yb;
    {   int t1; float tw;
        bsetup(gx - 0.125f, WW, xb, t1, tw);
        bsetup(gy - 0.125f, HH, yb, t1, tw);
    }

    // lane's 16 query channels (channels cg*16 .. cg*16+15) from bf16.
    float fq[16];
    {
        const unsigned int* q = (const unsigned int*)(fQ + (size_t)bn*CC) + cg*8;
        #pragma unroll
        for(int d=0; d<8; ++d){
            unsigned int u = q[d];
            fq[2*d+0] = __uint_as_float(u << 16);
            fq[2*d+1] = __uint_as_float(u & 0xffff0000u);
        }
    }

    __shared__ float dl[XN*YN];
    const float* base = fmapT + (size_t)b*HW*CC;
    #pragma unroll
    for(int it=0; it<4; ++it){
        int p = wid*30 + it*8 + sub;          // wave owns 30 pixels
        bool act = (it < 3) || (sub < 6);
        int pc = act ? p : (wid*30 + 29);
        int ky = pc / XN, kx = pc - ky*XN;
        int py = yb + ky; if(py > HH-1) py = HH-1;
        int px = xb + kx; if(px > WW-1) px = WW-1;
        const float4* row = (const float4*)(base + (size_t)(py*WW + px)*CC) + cg*4;
        float4 v0 = row[0], v1 = row[1], v2 = row[2], v3 = row[3];
        float s;
        s  = fq[0]*v0.x + fq[1]*v0.y + fq[2]*v0.z + fq[3]*v0.w;
        s += fq[4]*v1.x + fq[5]*v1.y + fq[6]*v1.z + fq[7]*v1.w;
        s += fq[8]*v2.x + fq[9]*v2.y + fq[10]*v2.z + fq[11]*v2.w;
        s += fq[12]*v3.x + fq[13]*v3.y + fq[14]*v3.z + fq[15]*v3.w;
        s += __shfl_xor(s, 1);
        s += __shfl_xor(s, 2);
        s += __shfl_xor(s, 4);
        if(cg==0 && act) dl[p] = s;
    }
    __syncthreads();

    float logit = -INFINITY, wcx = 0.f, wcy = 0.f;
    if(tid < SS){
        int i = tid % 9, j = tid / 9;
        wcx = gx + (-0.125f + 0.03125f*(float)i);
        wcy = gy + (-0.125f + 0.03125f*(float)j);
        int x0,x1,y0,y1; float wx,wy;
        bsetup(wcx, WW, x0,x1,wx);
        bsetup(wcy, HH, y0,y1,wy);
        int r0 = (y0-yb)*XN - xb, r1 = (y1-yb)*XN - xb;
        float d00=dl[r0+x0], d01=dl[r0+x1], d10=dl[r1+x0], d11=dl[r1+x1];
        logit = d00*(1.f-wx)*(1.f-wy) + d01*wx*(1.f-wy) + d10*(1.f-wx)*wy + d11*wx*wy;
    }

    float M = logit;
    #pragma unroll
    for(int m=1; m<64; m<<=1) M = fmaxf(M, __shfl_xor(M, m));
    __shared__ float mred[4];
    if(lane==0) mred[wid] = M;
    __syncthreads();
    M = fmaxf(fmaxf(mred[0],mred[1]), fmaxf(mred[2],mred[3]));

    float w = (tid < SS) ? __expf(logit - M) : 0.f;
    float v0=w, v1=w*wcx, v2=w*wcy, v3=w*wcx*wcx, v4=w*wcy*wcy;
    #pragma unroll
    for(int m=1; m<64; m<<=1){
        v0 += __shfl_xor(v0, m);
        v1 += __shfl_xor(v1, m);
        v2 += __shfl_xor(v2, m);
        v3 += __shfl_xor(v3, m);
        v4 += __shfl_xor(v4, m);
    }
    __shared__ float sred[4][5];
    if(lane==0){ sred[wid][0]=v0; sred[wid][1]=v1; sred[wid][2]=v2; sred[wid][3]=v3; sred[wid][4]=v4; }
    __syncthreads();
    if(tid==0){
        float S  = sred[0][0]+sred[1][0]+sred[2][0]+sred[3][0];
        float ex = (sred[0][1]+sred[1][1]+sred[2][1]+sred[3][1])/S;
        float ey = (sred[0][2]+sred[1][2]+sred[2][2]+sred[3][2])/S;
        float vx = (sred[0][3]+sred[1][3]+sred[2][3]+sred[3][3])/S - ex*ex;
        float vy = (sred[0][4]+sred[1][4]+sred[2][4]+sred[3][4])/S - ey*ey;
        float sd = sqrtf(fmaxf(vx,1e-6f)) + sqrtf(fmaxf(vy,1e-6f));
        float h = (float)hI[0], wimg = (float)wI[0];
        outW[(size_t)bn*2+0] = (ex+1.0f)*0.5f*(wimg-1.0f);
        outW[(size_t)bn*2+1] = (ey+1.0f)*0.5f*(h-1.0f);
        outStd[bn] = sd;
    }
}

extern "C" void kernel_launch(void* const* d_in, const int* in_sizes, int n_in,
                              void* d_out, int out_size, void* d_ws, size_t ws_size,
                              hipStream_t stream){
    const float* xf1 = (const float*)d_in[0];
    const float* xf2 = (const float*)d_in[1];
    const float* c1n = (const float*)d_in[2];
    const float* c2n = (const float*)d_in[3];
    const int* h1 = (const int*)d_in[4];
    const int* w1 = (const int*)d_in[5];
    const int* h2 = (const int*)d_in[6];
    const int* w2 = (const int*)d_in[7];
    float* out = (float*)d_out;
    float* ws = (float*)d_ws;

    float* xf1t = ws;                                   // B*HW*C f32
    float* xf2t = xf1t + (size_t)BB*HW*CC;
    __hip_bfloat16* f1b = (__hip_bfloat16*)(xf2t + (size_t)BB*HW*CC);   // B*N*C bf16
    __hip_bfloat16* f2b = f1b + (size_t)BB*NN*CC;
    float* wsRow = (float*)(f2b + (size_t)BB*NN*CC);    // B*N*NTILE*5 f32
    float* wsCol = wsRow + (size_t)BB*NN*NTILE*5;

    float* o_coord1 = out + 0;
    float* o_coord2 = out + 12288;
    float* o_g1     = out + 24576;
    float* o_g2     = out + 36864;
    float* o_w1     = out + 49152;
    float* o_w2     = out + 61440;
    float* o_g1n    = out + 73728;
    float* o_g2n    = out + 86016;
    float* o_std1   = out + 98304;
    float* o_std2   = out + 104448;
    float* o_wstd1  = out + 110592;
    float* o_wstd2  = out + 116736;
    float* o_valid  = out + 122880;

    hipLaunchKernelGGL(k_normT, dim3(2*BB*HW), dim3(128), 0, stream, xf1, xf2, xf1t, xf2t);
    hipLaunchKernelGGL(k_feats, dim3(2*BB*NN), dim3(128), 0, stream,
                       xf1, xf2, c1n, c2n, f1b, f2b, o_coord1, o_coord2, h1, w1, h2, w2);
    hipLaunchKernelGGL(k_corr, dim3(BB*NTILE*NTILE), dim3(256), 0, stream,
                       f1b, f2b, c1n, c2n, wsRow, wsCol, h1, w1, h2, w2);
    hipLaunchKernelGGL(k_red, dim3((2*BB*NN+255)/256), dim3(256), 0, stream,
                       wsRow, wsCol, o_g1, o_g1n, o_std1, o_g2, o_g2n, o_std2, o_valid,
                       h1, w1, h2, w2);
    hipLaunchKernelGGL(k_win2, dim3(2*BB*NN), dim3(256), 0, stream,
                       f1b, f2b, xf1t, xf2t, o_g1n, o_g2n,
                       o_w1, o_wstd1, o_w2, o_wstd2, h1, w1, h2, w2);
}

// Round 5
// 89.930 us; speedup vs baseline: 21.0957x; 1.4364x over previous
//
#include <hip/hip_runtime.h>
#include <hip/hip_bf16.h>
#include <math.h>

#define BB 2
#define CC 128
#define HH 60
#define WW 80
#define NN 3072
#define TT 16.0f
#define SS 81
#define HW (HH*WW)
#define NTILE 24   // 3072/128
#define LDA 136    // 128 + 8 bf16 pad
#define XN 12
#define YN 10

typedef __attribute__((ext_vector_type(8))) short short8;
typedef __attribute__((ext_vector_type(4))) float f32x4;
typedef _Float16 hf;
typedef _Float16 __attribute__((ext_vector_type(2))) h2;

#if __has_builtin(__builtin_amdgcn_fdot2)
#define FDOT2(a,b,c) __builtin_amdgcn_fdot2((a),(b),(c),false)
#else
#define FDOT2(a,b,c) ((c) + (float)(a).x*(float)(b).x + (float)(a).y*(float)(b).y)
#endif

__device__ __forceinline__ void bsetup(float cn, int L, int& i0, int& i1, float& w){
    float x = (cn + 1.0f) * 0.5f * (float)(L - 1);
    float x0 = floorf(x);
    w = x - x0;
    int xi = (int)x0;
    i0 = xi < 0 ? 0 : (xi > L - 1 ? L - 1 : xi);
    i1 = (i0 + 1 > L - 1) ? L - 1 : (i0 + 1);
}

// Transpose + per-pixel L2 stats. Per 32-pixel tile: coalesced channel-major reads
// -> LDS -> per-pixel sumsq -> write (B,H,W,C) f16 raw map AND f16 T*normalized map.
__global__ __launch_bounds__(256) void k_normT(
        const float* __restrict__ xf1, const float* __restrict__ xf2,
        hf* __restrict__ xf1r, hf* __restrict__ xf2r,
        hf* __restrict__ xf1t, hf* __restrict__ xf2t){
    int idx = blockIdx.x;
    int map = idx / (BB*(HW/32));
    int rem = idx % (BB*(HW/32));
    int b   = rem / (HW/32);
    int hw0 = (rem % (HW/32)) * 32;
    const float* src = (map ? xf2 : xf1) + (size_t)b*CC*HW + hw0;
    hf* dstR = (map ? xf2r : xf1r) + ((size_t)(b*HW + hw0))*CC;
    hf* dstT = (map ? xf2t : xf1t) + ((size_t)(b*HW + hw0))*CC;

    __shared__ float tile[CC][33];
    int tid = threadIdx.x;
    {
        int p = tid & 31, c0 = tid >> 5;
        #pragma unroll
        for(int i=0;i<16;i++){
            int c = i*8 + c0;
            tile[c][p] = src[(size_t)c*HW + p];
        }
    }
    __syncthreads();
    int q = tid >> 3, l = tid & 7;     // pixel q, 16 channels per lane
    float v[16];
    float ss = 0.f;
    #pragma unroll
    for(int k=0;k<16;k++){ v[k] = tile[l*16+k][q]; ss += v[k]*v[k]; }
    ss += __shfl_xor(ss,1); ss += __shfl_xor(ss,2); ss += __shfl_xor(ss,4);
    float inv = 1.0f / sqrtf(ss + 1e-12f);
    float tsc = TT * inv;
    union { hf h[16]; uint4 u[2]; } R, T;
    #pragma unroll
    for(int k=0;k<16;k++){ R.h[k] = (hf)v[k]; T.h[k] = (hf)(v[k]*tsc); }
    uint4* oR = (uint4*)(dstR + (size_t)q*CC + l*16);
    uint4* oT = (uint4*)(dstT + (size_t)q*CC + l*16);
    oR[0] = R.u[0]; oR[1] = R.u[1];
    oT[0] = T.u[0]; oT[1] = T.u[1];
}

// Bilinear sample RAW transposed f16 map, L2-normalize -> bf16 features + denormed coords.
// One wave per query, 2 channels per lane, all-coalesced corner row reads, pure-shfl reduce.
__global__ __launch_bounds__(64) void k_feats(
        const hf* __restrict__ xf1r, const hf* __restrict__ xf2r,
        const float* __restrict__ c1n, const float* __restrict__ c2n,
        __hip_bfloat16* __restrict__ f1b, __hip_bfloat16* __restrict__ f2b,
        float* __restrict__ o_coord1, float* __restrict__ o_coord2,
        const int* __restrict__ h1I, const int* __restrict__ w1I,
        const int* __restrict__ h2I, const int* __restrict__ w2I){
    int gid = blockIdx.x;
    int dir = gid / (BB*NN);
    int bn  = gid % (BB*NN);
    int b = bn / NN;
    const hf* raw = dir ? xf2r : xf1r;
    const float* cn = dir ? c2n : c1n;
    __hip_bfloat16* fOutB = dir ? f2b : f1b;
    float* coordOut = dir ? o_coord2 : o_coord1;
    const int* hI = dir ? h2I : h1I;
    const int* wI = dir ? w2I : w1I;

    int t = threadIdx.x;   // 0..63, channels 2t,2t+1
    float cnx = cn[(size_t)bn*2+0], cny = cn[(size_t)bn*2+1];
    int x0,x1,y0,y1; float wx,wy;
    bsetup(cnx, WW, x0,x1,wx);
    bsetup(cny, HH, y0,y1,wy);
    const hf* base = raw + (size_t)(b*HW)*CC;
    const uint* r00 = (const uint*)(base + (size_t)(y0*WW+x0)*CC) + t;
    const uint* r01 = (const uint*)(base + (size_t)(y0*WW+x1)*CC) + t;
    const uint* r10 = (const uint*)(base + (size_t)(y1*WW+x0)*CC) + t;
    const uint* r11 = (const uint*)(base + (size_t)(y1*WW+x1)*CC) + t;
    union { uint u; h2 v; } u00, u01, u10, u11;
    u00.u = *r00; u01.u = *r01; u10.u = *r10; u11.u = *r11;
    float w00=(1.f-wx)*(1.f-wy), w01=wx*(1.f-wy), w10=(1.f-wx)*wy, w11=wx*wy;
    float fx = w00*(float)u00.v.x + w01*(float)u01.v.x + w10*(float)u10.v.x + w11*(float)u11.v.x;
    float fy = w00*(float)u00.v.y + w01*(float)u01.v.y + w10*(float)u10.v.y + w11*(float)u11.v.y;
    float ss = fx*fx + fy*fy;
    #pragma unroll
    for(int m=1;m<64;m<<=1) ss += __shfl_xor(ss, m);
    float inv = 1.0f / sqrtf(ss + 1e-12f);
    unsigned short blo = __bfloat16_as_ushort(__float2bfloat16(fx*inv));
    unsigned short bhi = __bfloat16_as_ushort(__float2bfloat16(fy*inv));
    ((uint*)(fOutB + (size_t)bn*CC))[t] = ((uint)bhi << 16) | blo;
    if(t==0){
        float h=(float)hI[0], w=(float)wI[0];
        coordOut[(size_t)bn*2+0] = (cnx+1.0f)*0.5f*(w-1.0f);
        coordOut[(size_t)bn*2+1] = (cny+1.0f)*0.5f*(h-1.0f);
    }
}

// Fused correlation: ONE bf16-MFMA GEMM pass producing BOTH row (p12) and col (p21)
// partial softmax statistics.
__global__ __launch_bounds__(256,2) void k_corr(
        const __hip_bfloat16* __restrict__ f1b, const __hip_bfloat16* __restrict__ f2b,
        const float* __restrict__ c1n, const float* __restrict__ c2n,
        float* __restrict__ wsRow, float* __restrict__ wsCol,
        const int* __restrict__ h1I, const int* __restrict__ w1I,
        const int* __restrict__ h2I, const int* __restrict__ w2I){
    int blk = blockIdx.x;
    int b   = blk / (NTILE*NTILE);
    int rem = blk % (NTILE*NTILE);
    int nt = rem / NTILE, mt = rem % NTILE;
    int n0 = nt*128, m0 = mt*128;
    int tid = threadIdx.x;
    int lane = tid & 63, wid = tid >> 6;
    int wr = wid >> 1, wc = wid & 1;
    int lr = lane & 15, lh = lane >> 4;

    __shared__ __align__(16) unsigned short As[128*LDA];
    __shared__ __align__(16) unsigned short Bs[128*LDA];
    __shared__ float cn1s[128*2];
    __shared__ float cn2s[128*2];
    __shared__ float rowPart[2][128][5];
    __shared__ float colPart[2][128][5];

    {
        const unsigned short* gA = (const unsigned short*)f1b + ((size_t)b*NN + n0)*CC;
        const unsigned short* gB = (const unsigned short*)f2b + ((size_t)b*NN + m0)*CC;
        #pragma unroll
        for(int it=0; it<8; ++it){
            int idx = tid + it*256;
            int r = idx >> 4, q = idx & 15;
            *(uint4*)(As + r*LDA + q*8) = *(const uint4*)(gA + r*CC + q*8);
            *(uint4*)(Bs + r*LDA + q*8) = *(const uint4*)(gB + r*CC + q*8);
        }
        if(tid < 128){
            cn1s[tid*2+0] = c1n[((size_t)b*NN + n0 + tid)*2+0];
            cn1s[tid*2+1] = c1n[((size_t)b*NN + n0 + tid)*2+1];
        } else {
            int t = tid - 128;
            cn2s[t*2+0] = c2n[((size_t)b*NN + m0 + t)*2+0];
            cn2s[t*2+1] = c2n[((size_t)b*NN + m0 + t)*2+1];
        }
    }
    __syncthreads();

    f32x4 acc[4][4] = {};
    const unsigned short* aBase = As + (wr*64 + lr)*LDA + lh*8;
    const unsigned short* bBase = Bs + (wc*64 + lr)*LDA + lh*8;
    #pragma unroll
    for(int ks=0; ks<4; ++ks){
        short8 afr[4], bfr[4];
        #pragma unroll
        for(int i=0;i<4;i++) afr[i] = *(const short8*)(aBase + i*16*LDA + ks*32);
        #pragma unroll
        for(int j=0;j<4;j++) bfr[j] = *(const short8*)(bBase + j*16*LDA + ks*32);
        #pragma unroll
        for(int i=0;i<4;i++)
            #pragma unroll
            for(int j=0;j<4;j++)
                acc[i][j] = __builtin_amdgcn_mfma_f32_16x16x32_bf16(afr[i], bfr[j], acc[i][j], 0,0,0);
    }

    float h1f=(float)h1I[0], w1f=(float)w1I[0], h2f=(float)h2I[0], w2f=(float)w2I[0];
    float sx2 = 0.5f*(w2f-1.0f), sy2 = 0.5f*(h2f-1.0f);
    float sx1 = 0.5f*(w1f-1.0f), sy1 = 0.5f*(h1f-1.0f);

    float cx2[4], cy2[4], cxx2[4], cyy2[4];
    #pragma unroll
    for(int j=0;j<4;j++){
        int ml = wc*64 + j*16 + lr;
        float cnx = cn2s[ml*2+0], cny = cn2s[ml*2+1];
        cx2[j] = (cnx+1.f)*sx2; cy2[j] = (cny+1.f)*sy2;
        cxx2[j] = cnx*cnx; cyy2[j] = cny*cny;
    }
    float colA[4][5] = {};
    #pragma unroll
    for(int i=0;i<4;i++){
        #pragma unroll
        for(int r=0;r<4;r++){
            int nl = wr*64 + i*16 + lh*4 + r;
            float cnx1 = cn1s[nl*2+0], cny1 = cn1s[nl*2+1];
            float cx1=(cnx1+1.f)*sx1, cy1=(cny1+1.f)*sy1;
            float cxx1=cnx1*cnx1, cyy1=cny1*cny1;
            float rs=0.f, rax=0.f, ray=0.f, raxx=0.f, rayy=0.f;
            #pragma unroll
            for(int j=0;j<4;j++){
                float wgt = __expf(fmaf(TT, acc[i][j][r], -16.0f));
                rs += wgt;
                rax  = fmaf(wgt, cx2[j],  rax);
                ray  = fmaf(wgt, cy2[j],  ray);
                raxx = fmaf(wgt, cxx2[j], raxx);
                rayy = fmaf(wgt, cyy2[j], rayy);
                colA[j][0] += wgt;
                colA[j][1] = fmaf(wgt, cx1,  colA[j][1]);
                colA[j][2] = fmaf(wgt, cy1,  colA[j][2]);
                colA[j][3] = fmaf(wgt, cxx1, colA[j][3]);
                colA[j][4] = fmaf(wgt, cyy1, colA[j][4]);
            }
            #pragma unroll
            for(int msk=1; msk<16; msk<<=1){
                rs   += __shfl_xor(rs,   msk);
                rax  += __shfl_xor(rax,  msk);
                ray  += __shfl_xor(ray,  msk);
                raxx += __shfl_xor(raxx, msk);
                rayy += __shfl_xor(rayy, msk);
            }
            if(lr==0){
                float* p = rowPart[wc][nl];
                p[0]=rs; p[1]=rax; p[2]=ray; p[3]=raxx; p[4]=rayy;
            }
        }
    }
    #pragma unroll
    for(int j=0;j<4;j++){
        #pragma unroll
        for(int msk=16; msk<64; msk<<=1){
            #pragma unroll
            for(int c=0;c<5;c++) colA[j][c] += __shfl_xor(colA[j][c], msk);
        }
        if(lh==0){
            int ml = wc*64 + j*16 + lr;
            float* p = colPart[wr][ml];
            #pragma unroll
            for(int c=0;c<5;c++) p[c] = colA[j][c];
        }
    }
    __syncthreads();

    if(tid < 128){
        float* o = wsRow + (((size_t)b*NN + n0 + tid)*NTILE + mt)*5;
        #pragma unroll
        for(int c=0;c<5;c++) o[c] = rowPart[0][tid][c] + rowPart[1][tid][c];
    } else {
        int t = tid - 128;
        float* o = wsCol + (((size_t)b*NN + m0 + t)*NTILE + nt)*5;
        #pragma unroll
        for(int c=0;c<5;c++) o[c] = colPart[0][t][c] + colPart[1][t][c];
    }
}

// Combine NTILE partials per point, finalize g / gn / std; also writes valid flags.
__global__ __launch_bounds__(256) void k_red(
        const float* __restrict__ wsRow, const float* __restrict__ wsCol,
        float* __restrict__ o_g1, float* __restrict__ o_g1n, float* __restrict__ o_std1,
        float* __restrict__ o_g2, float* __restrict__ o_g2n, float* __restrict__ o_std2,
        float* __restrict__ o_valid,
        const int* __restrict__ h1I, const int* __restrict__ w1I,
        const int* __restrict__ h2I, const int* __restrict__ w2I){
    int p = blockIdx.x*256 + threadIdx.x;
    if(p >= 2*BB*NN) return;
    o_valid[p] = 1.0f;
    int dir = p / (BB*NN);
    int i   = p % (BB*NN);
    const float* src = (dir ? wsCol : wsRow) + (size_t)i*NTILE*5;
    float S=0.f, AX=0.f, AY=0.f, AXX=0.f, AYY=0.f;
    for(int t=0;t<NTILE;t++){
        S   += src[t*5+0];
        AX  += src[t*5+1];
        AY  += src[t*5+2];
        AXX += src[t*5+3];
        AYY += src[t*5+4];
    }
    float hf_ = dir ? (float)h1I[0] : (float)h2I[0];
    float wf = dir ? (float)w1I[0] : (float)w2I[0];
    float gx = AX/S, gy = AY/S;
    float gnx = gx * (2.0f/(wf-1.0f)) - 1.0f;
    float gny = gy * (2.0f/(hf_-1.0f)) - 1.0f;
    float vx = AXX/S - gnx*gnx;
    float vy = AYY/S - gny*gny;
    float sd = sqrtf(fmaxf(vx,1e-6f)) + sqrtf(fmaxf(vy,1e-6f));
    float* oG  = dir ? o_g2  : o_g1;
    float* oGn = dir ? o_g2n : o_g1n;
    float* oSd = dir ? o_std2: o_std1;
    oG[(size_t)i*2+0]=gx;  oG[(size_t)i*2+1]=gy;
    oGn[(size_t)i*2+0]=gnx; oGn[(size_t)i*2+1]=gny;
    oSd[i]=sd;
}

// Window refinement. Phase 1: one 128-ch dot per distinct window pixel (<=12x10 grid),
// 8 pixels/wave concurrently, 8-lane channel groups, f16 rows (2x dwordx4) + fdot2.
// Phase 2: 81 threads bilinear-combine -> softmax -> moments.
__global__ __launch_bounds__(256) void k_win2(
        const __hip_bfloat16* __restrict__ f1b, const __hip_bfloat16* __restrict__ f2b,
        const hf* __restrict__ xf1t, const hf* __restrict__ xf2t,
        const float* __restrict__ g1n, const float* __restrict__ g2n,
        float* __restrict__ o_w1, float* __restrict__ o_wstd1,
        float* __restrict__ o_w2, float* __restrict__ o_wstd2,
        const int* __restrict__ h1I, const int* __restrict__ w1I,
        const int* __restrict__ h2I, const int* __restrict__ w2I){
    int gid = blockIdx.x;
    int dir = gid / (BB*NN);
    int bn  = gid % (BB*NN);
    int b   = bn / NN;
    const __hip_bfloat16* fQ = dir ? f2b : f1b;
    const hf* fmapT          = dir ? xf1t : xf2t;
    const float* center      = dir ? g2n  : g1n;
    const int* hI            = dir ? h1I  : h2I;
    const int* wI            = dir ? w1I  : w2I;
    float* outW              = dir ? o_w2 : o_w1;
    float* outStd            = dir ? o_wstd2 : o_wstd1;

    int tid = threadIdx.x;
    int lane = tid & 63, wid = tid >> 6;
    int cg  = lane & 7;    // 16-channel group
    int sub = lane >> 3;   // pixel sub-index within wave iter

    float gx = center[(size_t)bn*2+0], gy = center[(size_t)bn*2+1];
    int xb, yb;
    {   int t1; float tw;
        bsetup(gx - 0.125f, WW, xb, t1, tw);
        bsetup(gy - 0.125f, HH, yb, t1, tw);
    }

    // lane's 16 query channels as 8 f16 pairs (bf16 -> f32 -> f16, exact)
    h2 fq2[8];
    {
        const uint* q = (const uint*)(fQ + (size_t)bn*CC) + cg*8;
        #pragma unroll
        for(int d=0; d<8; ++d){
            uint u = q[d];
            float lo = __uint_as_float(u << 16);
            float hi = __uint_as_float(u & 0xffff0000u);
            fq2[d].x = (hf)lo; fq2[d].y = (hf)hi;
        }
    }

    __shared__ float dl[XN*YN];
    const hf* base = fmapT + (size_t)b*HW*CC;
    #pragma unroll
    for(int it=0; it<4; ++it){
        int p = wid*30 + it*8 + sub;          // wave owns 30 pixels
        bool act = (it < 3) || (sub < 6);
        int pc = act ? p : (wid*30 + 29);
        int ky = pc / XN, kx = pc - ky*XN;
        int py = yb + ky; if(py > HH-1) py = HH-1;
        int px = xb + kx; if(px > WW-1) px = WW-1;
        const uint4* row = (const uint4*)(base + (size_t)(py*WW + px)*CC) + cg*2;
        union { uint4 u[2]; h2 v[8]; } U;
        U.u[0] = row[0]; U.u[1] = row[1];
        float s = 0.f;
        #pragma unroll
        for(int d=0; d<8; ++d) s = FDOT2(fq2[d], U.v[d], s);
        s += __shfl_xor(s, 1);
        s += __shfl_xor(s, 2);
        s += __shfl_xor(s, 4);
        if(cg==0 && act) dl[p] = s;
    }
    __syncthreads();

    float logit = -INFINITY, wcx = 0.f, wcy = 0.f;
    if(tid < SS){
        int i = tid % 9, j = tid / 9;
        wcx = gx + (-0.125f + 0.03125f*(float)i);
        wcy = gy + (-0.125f + 0.03125f*(float)j);
        int x0,x1,y0,y1; float wx,wy;
        bsetup(wcx, WW, x0,x1,wx);
        bsetup(wcy, HH, y0,y1,wy);
        int r0 = (y0-yb)*XN - xb, r1 = (y1-yb)*XN - xb;
        float d00=dl[r0+x0], d01=dl[r0+x1], d10=dl[r1+x0], d11=dl[r1+x1];
        logit = d00*(1.f-wx)*(1.f-wy) + d01*wx*(1.f-wy) + d10*(1.f-wx)*wy + d11*wx*wy;
    }

    float M = logit;
    #pragma unroll
    for(int m=1; m<64; m<<=1) M = fmaxf(M, __shfl_xor(M, m));
    __shared__ float mred[4];
    if(lane==0) mred[wid] = M;
    __syncthreads();
    M = fmaxf(fmaxf(mred[0],mred[1]), fmaxf(mred[2],mred[3]));

    float w = (tid < SS) ? __expf(logit - M) : 0.f;
    float v0=w, v1=w*wcx, v2=w*wcy, v3=w*wcx*wcx, v4=w*wcy*wcy;
    #pragma unroll
    for(int m=1; m<64; m<<=1){
        v0 += __shfl_xor(v0, m);
        v1 += __shfl_xor(v1, m);
        v2 += __shfl_xor(v2, m);
        v3 += __shfl_xor(v3, m);
        v4 += __shfl_xor(v4, m);
    }
    __shared__ float sred[4][5];
    if(lane==0){ sred[wid][0]=v0; sred[wid][1]=v1; sred[wid][2]=v2; sred[wid][3]=v3; sred[wid][4]=v4; }
    __syncthreads();
    if(tid==0){
        float S  = sred[0][0]+sred[1][0]+sred[2][0]+sred[3][0];
        float ex = (sred[0][1]+sred[1][1]+sred[2][1]+sred[3][1])/S;
        float ey = (sred[0][2]+sred[1][2]+sred[2][2]+sred[3][2])/S;
        float vx = (sred[0][3]+sred[1][3]+sred[2][3]+sred[3][3])/S - ex*ex;
        float vy = (sred[0][4]+sred[1][4]+sred[2][4]+sred[3][4])/S - ey*ey;
        float sd = sqrtf(fmaxf(vx,1e-6f)) + sqrtf(fmaxf(vy,1e-6f));
        float h = (float)hI[0], wimg = (float)wI[0];
        outW[(size_t)bn*2+0] = (ex+1.0f)*0.5f*(wimg-1.0f);
        outW[(size_t)bn*2+1] = (ey+1.0f)*0.5f*(h-1.0f);
        outStd[bn] = sd;
    }
}

extern "C" void kernel_launch(void* const* d_in, const int* in_sizes, int n_in,
                              void* d_out, int out_size, void* d_ws, size_t ws_size,
                              hipStream_t stream){
    const float* xf1 = (const float*)d_in[0];
    const float* xf2 = (const float*)d_in[1];
    const float* c1n = (const float*)d_in[2];
    const float* c2n = (const float*)d_in[3];
    const int* h1 = (const int*)d_in[4];
    const int* w1 = (const int*)d_in[5];
    const int* h2 = (const int*)d_in[6];
    const int* w2 = (const int*)d_in[7];
    float* out = (float*)d_out;

    hf* xf1r = (hf*)d_ws;                               // B*HW*C f16 raw transposed
    hf* xf2r = xf1r + (size_t)BB*HW*CC;
    hf* xf1t = xf2r + (size_t)BB*HW*CC;                 // B*HW*C f16 T*normalized
    hf* xf2t = xf1t + (size_t)BB*HW*CC;
    __hip_bfloat16* f1b = (__hip_bfloat16*)(xf2t + (size_t)BB*HW*CC);   // B*N*C bf16
    __hip_bfloat16* f2b = f1b + (size_t)BB*NN*CC;
    float* wsRow = (float*)(f2b + (size_t)BB*NN*CC);    // B*N*NTILE*5 f32
    float* wsCol = wsRow + (size_t)BB*NN*NTILE*5;

    float* o_coord1 = out + 0;
    float* o_coord2 = out + 12288;
    float* o_g1     = out + 24576;
    float* o_g2     = out + 36864;
    float* o_w1     = out + 49152;
    float* o_w2     = out + 61440;
    float* o_g1n    = out + 73728;
    float* o_g2n    = out + 86016;
    float* o_std1   = out + 98304;
    float* o_std2   = out + 104448;
    float* o_wstd1  = out + 110592;
    float* o_wstd2  = out + 116736;
    float* o_valid  = out + 122880;

    hipLaunchKernelGGL(k_normT, dim3(2*BB*(HW/32)), dim3(256), 0, stream,
                       xf1, xf2, xf1r, xf2r, xf1t, xf2t);
    hipLaunchKernelGGL(k_feats, dim3(2*BB*NN), dim3(64), 0, stream,
                       xf1r, xf2r, c1n, c2n, f1b, f2b, o_coord1, o_coord2, h1, w1, h2, w2);
    hipLaunchKernelGGL(k_corr, dim3(BB*NTILE*NTILE), dim3(256), 0, stream,
                       f1b, f2b, c1n, c2n, wsRow, wsCol, h1, w1, h2, w2);
    hipLaunchKernelGGL(k_red, dim3((2*BB*NN+255)/256), dim3(256), 0, stream,
                       wsRow, wsCol, o_g1, o_g1n, o_std1, o_g2, o_g2n, o_std2, o_valid,
                       h1, w1, h2, w2);
    hipLaunchKernelGGL(k_win2, dim3(2*BB*NN), dim3(256), 0, stream,
                       f1b, f2b, xf1t, xf2t, o_g1n, o_g2n,
                       o_w1, o_wstd1, o_w2, o_wstd2, h1, w1, h2, w2);
}